// Round 10
// baseline (475.080 us; speedup 1.0000x reference)
//
#include <hip/hip_runtime.h>

#define N_NODES 50000
#define N_EDGES 800000
#define N_GRAPHS 64
#define F 256        // F_IN == F_HID
#define F_OUT 128
#define G_DIM 768    // 3*F
#define SCAN_NB ((N_NODES + 255) / 256)   // 196
#define POOL_CHUNKS 16

typedef unsigned short ushort_t;
typedef short short8 __attribute__((ext_vector_type(8)));
typedef short short4v __attribute__((ext_vector_type(4)));
typedef unsigned short ushort8 __attribute__((ext_vector_type(8)));
typedef unsigned short ushort4v __attribute__((ext_vector_type(4)));
typedef float float4v __attribute__((ext_vector_type(4)));
typedef unsigned int uint2v __attribute__((ext_vector_type(2)));

// ---- bf16 helpers (RNE) ----
__device__ __forceinline__ unsigned short f2bf(float f) {
    unsigned int u = __float_as_uint(f);
    u += 0x7FFFu + ((u >> 16) & 1u);
    return (unsigned short)(u >> 16);
}
__device__ __forceinline__ float bf2f(unsigned short s) {
    return __uint_as_float(((unsigned int)s) << 16);
}

// ---- async global->LDS, 16B per lane ----
__device__ __forceinline__ void gld_lds16(const void* gsrc, void* ldst) {
    __builtin_amdgcn_global_load_lds(
        (const __attribute__((address_space(1))) unsigned int*)gsrc,
        (__attribute__((address_space(3))) unsigned int*)ldst, 16, 0, 0);
}

// ---------------- fused: W1/W2 transposed hi/lo cast (blocks 0..511) + degree count ----------------
__global__ void prep_w_deg(const float* __restrict__ W1, const float* __restrict__ W2,
                           short* __restrict__ hi1, short* __restrict__ lo1,
                           short* __restrict__ hi2, short* __restrict__ lo2,
                           const int* __restrict__ dst, int* __restrict__ deg) {
    int blk = blockIdx.x;
    if (blk < 512) {
        const float* W = (blk < 256) ? W1 : W2;
        short* hi = (blk < 256) ? hi1 : hi2;
        short* lo = (blk < 256) ? lo1 : lo2;
        int n = blk & 255;
        int k = threadIdx.x;
        float v = W[k * 256 + n];
        unsigned short h = f2bf(v);
        hi[n * 256 + k] = (short)h;
        lo[n * 256 + k] = (short)f2bf(v - bf2f(h));
    } else {
        int e = (blk - 512) * 256 + threadIdx.x;
        if (e < N_EDGES) atomicAdd(&deg[dst[e]], 1);
    }
}

// ---------------- scan blocks + fused dinv ----------------
__global__ void scan_blocks(const int* __restrict__ deg, int* __restrict__ row_ptr,
                            int* __restrict__ block_tot, float* __restrict__ dinv) {
    __shared__ int sd[256];
    int t = threadIdx.x;
    int idx = blockIdx.x * 256 + t;
    int v = (idx < N_NODES) ? deg[idx] : 0;
    if (idx < N_NODES) dinv[idx] = rsqrtf((float)(v + 1));   // +1 self-loop
    sd[t] = v;
    __syncthreads();
    for (int off = 1; off < 256; off <<= 1) {
        int a = (t >= off) ? sd[t - off] : 0;
        __syncthreads();
        sd[t] += a;
        __syncthreads();
    }
    if (idx < N_NODES) row_ptr[idx] = sd[t] - v;
    if (t == 255) block_tot[blockIdx.x] = sd[255];
}

__global__ void scan_totals(int* block_tot) {
    __shared__ int sd[256];
    int t = threadIdx.x;
    int v = (t < SCAN_NB) ? block_tot[t] : 0;
    sd[t] = v;
    __syncthreads();
    for (int off = 1; off < 256; off <<= 1) {
        int a = (t >= off) ? sd[t - off] : 0;
        __syncthreads();
        sd[t] += a;
        __syncthreads();
    }
    if (t < SCAN_NB) block_tot[t] = sd[t] - v;
}

__global__ void add_offsets(int* __restrict__ row_ptr, const int* __restrict__ block_tot) {
    int idx = blockIdx.x * 256 + threadIdx.x;
    if (idx < N_NODES) row_ptr[idx] += block_tot[blockIdx.x];
    if (idx == 0) row_ptr[N_NODES] = N_EDGES;
}

// ---------------- bucket edges into CSR order; combined 8B record ----------------
// erec[pos] = { float bits of norm (dinv[s]*dinv[d]), src index }
__global__ void bucket_edges(const int* __restrict__ src, const int* __restrict__ dst,
                             const float* __restrict__ dinv,
                             const int* __restrict__ row_ptr, int* __restrict__ cursor,
                             uint2v* __restrict__ erec) {
    int e = blockIdx.x * blockDim.x + threadIdx.x;
    if (e < N_EDGES) {
        int d = dst[e];
        int s = src[e];
        int pos = row_ptr[d] + atomicAdd(&cursor[d], 1);
        uint2v r;
        r.x = __float_as_uint(dinv[s] * dinv[d]);
        r.y = (unsigned)s;
        erec[pos] = r;
    }
}

// ---------------- split-bf16 MFMA GEMM, fp32 A with in-register split ----------------
// hbf[M,256] = bf16( A[M,256] @ W[256,256] ); A fp32 row-major, W transposed hi/lo bf16.
// BM=64, BN=256 (single col-block): A read from HBM exactly once.
#define BM 64
#define BK 32
#define ASTRIDE 36   // padded floats/row: conflict-free b128 frag reads
__global__ __launch_bounds__(256) void gemm_mfma(
        const float* __restrict__ A,
        const short* __restrict__ Bthi, const short* __restrict__ Btlo,
        ushort_t* __restrict__ hbf, int M) {
    __shared__ float sA[BM * ASTRIDE];                 // 9216 B
    __shared__ short sBh[256 * BK], sBl[256 * BK];     // 16KB + 16KB
    int tid = threadIdx.x;
    int wave = tid >> 6, lane = tid & 63;
    int q = lane >> 4, t = lane & 15;
    int row0 = blockIdx.x * BM;
    int wc = wave * 64;            // wave's 64-col slice of N=256

    int lrow = lane >> 2;          // 0..15 (B staging)
    int lk = (lane & 3) * 8;       // k offset (shorts)
    int ar = tid >> 2;             // A staging: row 0..63
    int ak = tid & 3;              // A staging: 2 float4s at units ak, ak+4

    float4v acc[4][4] = {};
    for (int kt = 0; kt < 256; kt += BK) {
        // ---- A tile: global fp32 -> regs ----
        int ga = row0 + ar; if (ga >= M) ga = M - 1;   // clamp; never stored
        const float* ap = &A[(size_t)ga * 256 + kt + ak * 4];
        float4 a0 = *(const float4*)ap;
        float4 a1 = *(const float4*)(ap + 16);
        // ---- B tile: async global->LDS (row-major, as before) ----
#pragma unroll
        for (int j = 0; j < 4; ++j) {
            int n = wave * 64 + j * 16 + lrow;
            size_t boff = (size_t)n * 256 + kt + lk;
            int ldso = wave * 2048 + j * 512 + lane * 8;
            gld_lds16(&Bthi[boff], &sBh[ldso]);
            gld_lds16(&Btlo[boff], &sBl[ldso]);
        }
        // ---- A regs -> padded LDS ----
        *(float4*)&sA[ar * ASTRIDE + ak * 4] = a0;
        *(float4*)&sA[ar * ASTRIDE + (ak + 4) * 4] = a1;
        __syncthreads();
        // ---- fragments ----
        short8 ah[4], al[4], bh[4], bl[4];
#pragma unroll
        for (int mi = 0; mi < 4; ++mi) {
            int r = mi * 16 + t;
            const float* pa = &sA[r * ASTRIDE + q * 8];
            float4 f0 = *(const float4*)pa;
            float4 f1 = *(const float4*)(pa + 4);
            float fv[8] = {f0.x, f0.y, f0.z, f0.w, f1.x, f1.y, f1.z, f1.w};
            short8 h, l;
#pragma unroll
            for (int j = 0; j < 8; ++j) {
                unsigned short hh = f2bf(fv[j]);
                h[j] = (short)hh;
                l[j] = (short)f2bf(fv[j] - bf2f(hh));
            }
            ah[mi] = h; al[mi] = l;
        }
#pragma unroll
        for (int ni = 0; ni < 4; ++ni) {
            int n = wc + ni * 16 + t;
            bh[ni] = *(const short8*)&sBh[n * BK + q * 8];
            bl[ni] = *(const short8*)&sBl[n * BK + q * 8];
        }
#pragma unroll
        for (int mi = 0; mi < 4; ++mi)
#pragma unroll
            for (int ni = 0; ni < 4; ++ni) {
                acc[mi][ni] = __builtin_amdgcn_mfma_f32_16x16x32_bf16(ah[mi], bh[ni], acc[mi][ni], 0, 0, 0);
                acc[mi][ni] = __builtin_amdgcn_mfma_f32_16x16x32_bf16(ah[mi], bl[ni], acc[mi][ni], 0, 0, 0);
                acc[mi][ni] = __builtin_amdgcn_mfma_f32_16x16x32_bf16(al[mi], bh[ni], acc[mi][ni], 0, 0, 0);
            }
        __syncthreads();
    }
#pragma unroll
    for (int mi = 0; mi < 4; ++mi) {
        int gr0 = row0 + mi * 16 + q * 4;
#pragma unroll
        for (int rr = 0; rr < 4; ++rr) {
            int gr = gr0 + rr;
            if (gr < M) {
#pragma unroll
                for (int ni = 0; ni < 4; ++ni)
                    hbf[(size_t)gr * 256 + wc + ni * 16 + t] = f2bf(acc[mi][ni][rr]);
            }
        }
    }
}

// -------- CSR gather over bf16 h; 2 edges per wave-iteration; fused epilogue --------
// wave = node; half-wave (32 lanes x ushort8 = 512B) covers one full row.
// OUTBF16: write bf16 (feeds pooling); else fp32 (feeds gemm2, which splits on the fly).
template<bool OUTBF16>
__global__ __launch_bounds__(256) void gather_bf16(
        const int* __restrict__ row_ptr, const uint2v* __restrict__ erec,
        const float* __restrict__ dinv,
        const ushort_t* __restrict__ hbf, const float* __restrict__ b,
        float* __restrict__ outF, ushort_t* __restrict__ outBf) {
    int wave = threadIdx.x >> 6;
    int node = blockIdx.x * 4 + wave;      // N_NODES % 4 == 0
    int lane = threadIdx.x & 63;
    int g = lane >> 5;                      // half-wave: which of the 2 edges
    int hl = lane & 31;                     // feats hl*8 .. hl*8+7
    int beg = row_ptr[node], end = row_ptr[node + 1];
    float dd = dinv[node];
    float acc[8] = {};
    for (int cbeg = beg; cbeg < end; cbeg += 64) {
        int n = end - cbeg; if (n > 64) n = 64;
        uint2v er = {0u, 0u};
        if (lane < n) er = __builtin_nontemporal_load(&erec[cbeg + lane]);
        int sv = (int)er.y;
        float wv = __uint_as_float(er.x);
        for (int k = 0; k < n; k += 2) {
            int idx = k + g;                // <= 63 always; w==0 if idx>=n
            int s = __shfl(sv, idx);
            float w = __shfl(wv, idx);
            ushort8 hv = *(const ushort8*)&hbf[(size_t)s * 256 + hl * 8];
#pragma unroll
            for (int j = 0; j < 8; ++j)
                acc[j] = fmaf(bf2f(hv[j]), w, acc[j]);
        }
    }
    // combine the two half-waves
#pragma unroll
    for (int j = 0; j < 8; ++j) acc[j] += __shfl_xor(acc[j], 32);
    if (g == 0) {
        ushort8 sf = *(const ushort8*)&hbf[(size_t)node * 256 + hl * 8];
        float ws = dd * dd;
#pragma unroll
        for (int j = 0; j < 8; ++j)
            acc[j] = fmaxf(fmaf(bf2f(sf[j]), ws, acc[j]) + b[hl * 8 + j], 0.f);
        size_t o = (size_t)node * 256 + hl * 8;
        if (OUTBF16) {
            ushort8 hb;
#pragma unroll
            for (int j = 0; j < 8; ++j) hb[j] = f2bf(acc[j]);
            *(ushort8*)&outBf[o] = hb;
        } else {
            float4 v0 = make_float4(acc[0], acc[1], acc[2], acc[3]);
            float4 v1 = make_float4(acc[4], acc[5], acc[6], acc[7]);
            *(float4*)&outF[o] = v0;
            *(float4*)&outF[o + 4] = v1;
        }
    }
}

// ---------------- parallel triple pooling over bf16 h (1 wave/block) ----------------
__global__ __launch_bounds__(64) void pool_partial(
        const ushort_t* __restrict__ h, const int* __restrict__ batch,
        float* __restrict__ psum, int* __restrict__ pmaxi) {
    int g = blockIdx.x;
    int chunk = blockIdx.y;
    int lane = threadIdx.x;  // 64; lane covers feats lane*4..lane*4+3
    int lo = 0, hi = N_NODES;
    while (lo < hi) { int mid = (lo + hi) >> 1; if (batch[mid] < g) lo = mid + 1; else hi = mid; }
    int start = lo;
    lo = 0; hi = N_NODES;
    while (lo < hi) { int mid = (lo + hi) >> 1; if (batch[mid] < g + 1) lo = mid + 1; else hi = mid; }
    int end = lo;
    int len = end - start;
    if (len <= 0) return;
    int per = (len + POOL_CHUNKS - 1) / POOL_CHUNKS;
    int cs = start + chunk * per;
    int ce = cs + per; if (ce > end) ce = end;
    if (cs >= ce) return;
    float4 sum = make_float4(0.f, 0.f, 0.f, 0.f);
    float4 mx  = make_float4(0.f, 0.f, 0.f, 0.f);
    for (int n = cs; n < ce; ++n) {
        ushort4v u = *(const ushort4v*)&h[(size_t)n * 256 + lane * 4];
        float vx = bf2f(u.x), vy = bf2f(u.y), vz = bf2f(u.z), vw = bf2f(u.w);
        sum.x += vx; sum.y += vy; sum.z += vz; sum.w += vw;
        mx.x = fmaxf(mx.x, vx); mx.y = fmaxf(mx.y, vy);
        mx.z = fmaxf(mx.z, vz); mx.w = fmaxf(mx.w, vw);
    }
    float* ps = &psum[g * F + lane * 4];
    atomicAdd(&ps[0], sum.x); atomicAdd(&ps[1], sum.y);
    atomicAdd(&ps[2], sum.z); atomicAdd(&ps[3], sum.w);
    int* pm = &pmaxi[g * F + lane * 4];
    atomicMax(&pm[0], __float_as_int(mx.x)); atomicMax(&pm[1], __float_as_int(mx.y));
    atomicMax(&pm[2], __float_as_int(mx.z)); atomicMax(&pm[3], __float_as_int(mx.w));
}

// ---------------- final GEMM: out[64,128] = [mean|max|sum] @ Wfc + bfc ----------------
__global__ void final_gemm(const float* __restrict__ psum, const int* __restrict__ pmaxi,
                           const int* __restrict__ batch,
                           const float* __restrict__ Wfc, const float* __restrict__ bfc,
                           float* __restrict__ out) {
    int g = blockIdx.x;   // 64
    int o = threadIdx.x;  // 128
    __shared__ float row[G_DIM];
    __shared__ int s_cnt;
    if (threadIdx.x == 0) {
        int lo = 0, hi = N_NODES;
        while (lo < hi) { int mid = (lo + hi) >> 1; if (batch[mid] < g) lo = mid + 1; else hi = mid; }
        int start = lo;
        lo = 0; hi = N_NODES;
        while (lo < hi) { int mid = (lo + hi) >> 1; if (batch[mid] < g + 1) lo = mid + 1; else hi = mid; }
        s_cnt = lo - start;
    }
    __syncthreads();
    float inv = 1.0f / fmaxf((float)s_cnt, 1.0f);
    for (int i = threadIdx.x; i < F; i += 128) {
        float s = psum[g * F + i];
        row[i]       = s * inv;
        row[F + i]   = __int_as_float(pmaxi[g * F + i]);
        row[2*F + i] = s;
    }
    __syncthreads();
    float acc = bfc[o];
    for (int k = 0; k < G_DIM; ++k) acc += row[k] * Wfc[k * F_OUT + o];
    out[g * F_OUT + o] = acc;
}

extern "C" void kernel_launch(void* const* d_in, const int* in_sizes, int n_in,
                              void* d_out, int out_size, void* d_ws, size_t ws_size,
                              hipStream_t stream) {
    const float* x    = (const float*)d_in[0];
    const int*   ei   = (const int*)d_in[1];
    const int*   batch= (const int*)d_in[2];
    const float* W1   = (const float*)d_in[4];
    const float* b1   = (const float*)d_in[5];
    const float* W2   = (const float*)d_in[6];
    const float* b2   = (const float*)d_in[7];
    const float* Wfc  = (const float*)d_in[8];
    const float* bfc  = (const float*)d_in[9];
    float* out = (float*)d_out;

    const int* src = ei;
    const int* dst = ei + N_EDGES;

    const size_t NF = (size_t)N_NODES * F;   // 12.8M

    ushort_t* hbf = (ushort_t*)d_ws;         // [N,256] bf16 gemm out (25.6 MB)
    float* h1    = (float*)(hbf + NF);       // [N,256] fp32 gather1 out (51.2 MB)
    ushort_t* h2bf = (ushort_t*)h1;          // alias: gather2 bf16 out reuses h1 region
    short* w1hi  = (short*)(h1 + NF);        // 4x 64K shorts
    short* w1lo  = w1hi + 65536;
    short* w2hi  = w1lo + 65536;
    short* w2lo  = w2hi + 65536;
    float* dinv  = (float*)(w2lo + 65536);   // [N]
    int*   deg   = (int*)(dinv + N_NODES);   // [N]
    int*   cursor= deg + N_NODES;            // [N]
    int*   row_ptr = cursor + N_NODES;       // [N+1]
    int*   btot  = row_ptr + N_NODES + 1;    // [256]
    uint2v* erec = (uint2v*)(btot + 256);    // [E] 8B records (6.4 MB)
    float* psum  = (float*)(erec + N_EDGES); // [64][256]
    int*   pmaxi = (int*)(psum + N_GRAPHS * F);  // [64][256]

    // ---- degree + norm + CSR (+ W casts fused) ----
    hipMemsetAsync(deg, 0, 2 * N_NODES * sizeof(int), stream);   // deg + cursor
    prep_w_deg<<<512 + (N_EDGES + 255) / 256, 256, 0, stream>>>(
        W1, W2, w1hi, w1lo, w2hi, w2lo, dst, deg);
    scan_blocks<<<SCAN_NB, 256, 0, stream>>>(deg, row_ptr, btot, dinv);
    scan_totals<<<1, 256, 0, stream>>>(btot);
    add_offsets<<<SCAN_NB, 256, 0, stream>>>(row_ptr, btot);
    bucket_edges<<<(N_EDGES + 255) / 256, 256, 0, stream>>>(src, dst, dinv, row_ptr,
                                                            cursor, erec);

    int ggemm = (N_NODES + BM - 1) / BM;      // 782
    int ngb = N_NODES / 4;                    // 12500 blocks of 4 waves

    // ---- layer 1 ----
    gemm_mfma<<<ggemm, 256, 0, stream>>>(x, w1hi, w1lo, hbf, N_NODES);
    gather_bf16<false><<<ngb, 256, 0, stream>>>(row_ptr, erec, dinv, hbf, b1,
                                                h1, nullptr);    // h1 fp32

    // ---- layer 2 ----
    gemm_mfma<<<ggemm, 256, 0, stream>>>(h1, w2hi, w2lo, hbf, N_NODES);
    gather_bf16<true><<<ngb, 256, 0, stream>>>(row_ptr, erec, dinv, hbf, b2,
                                               nullptr, h2bf);   // h2 bf16

    // ---- pooling + classifier ----
    hipMemsetAsync(psum, 0, N_GRAPHS * F * 2 * sizeof(float), stream);
    pool_partial<<<dim3(N_GRAPHS, POOL_CHUNKS), 64, 0, stream>>>(h2bf, batch, psum, pmaxi);
    final_gemm<<<N_GRAPHS, F_OUT, 0, stream>>>(psum, pmaxi, batch, Wfc, bfc, out);
}

// Round 11
// 430.385 us; speedup vs baseline: 1.1038x; 1.1038x over previous
//
#include <hip/hip_runtime.h>

#define N_NODES 50000
#define N_EDGES 800000
#define N_GRAPHS 64
#define F 256        // F_IN == F_HID
#define F_OUT 128
#define G_DIM 768    // 3*F
#define SCAN_NB ((N_NODES + 255) / 256)   // 196
#define POOL_CHUNKS 16

typedef unsigned short ushort_t;
typedef short short8 __attribute__((ext_vector_type(8)));
typedef short short4v __attribute__((ext_vector_type(4)));
typedef unsigned short ushort8 __attribute__((ext_vector_type(8)));
typedef unsigned short ushort4v __attribute__((ext_vector_type(4)));
typedef float float4v __attribute__((ext_vector_type(4)));
typedef unsigned int uint2v __attribute__((ext_vector_type(2)));

// ---- bf16 helpers (RNE) ----
__device__ __forceinline__ unsigned short f2bf(float f) {
    unsigned int u = __float_as_uint(f);
    u += 0x7FFFu + ((u >> 16) & 1u);
    return (unsigned short)(u >> 16);
}
__device__ __forceinline__ float bf2f(unsigned short s) {
    return __uint_as_float(((unsigned int)s) << 16);
}

// ---- async global->LDS, 16B per lane ----
__device__ __forceinline__ void gld_lds16(const void* gsrc, void* ldst) {
    __builtin_amdgcn_global_load_lds(
        (const __attribute__((address_space(1))) unsigned int*)gsrc,
        (__attribute__((address_space(3))) unsigned int*)ldst, 16, 0, 0);
}

// ---------------- fused: W1/W2 transposed hi/lo cast (blocks 0..511) + degree count ----------------
__global__ void prep_w_deg(const float* __restrict__ W1, const float* __restrict__ W2,
                           short* __restrict__ hi1, short* __restrict__ lo1,
                           short* __restrict__ hi2, short* __restrict__ lo2,
                           const int* __restrict__ dst, int* __restrict__ deg) {
    int blk = blockIdx.x;
    if (blk < 512) {
        const float* W = (blk < 256) ? W1 : W2;
        short* hi = (blk < 256) ? hi1 : hi2;
        short* lo = (blk < 256) ? lo1 : lo2;
        int n = blk & 255;
        int k = threadIdx.x;
        float v = W[k * 256 + n];
        unsigned short h = f2bf(v);
        hi[n * 256 + k] = (short)h;
        lo[n * 256 + k] = (short)f2bf(v - bf2f(h));
    } else {
        int e = (blk - 512) * 256 + threadIdx.x;
        if (e < N_EDGES) atomicAdd(&deg[dst[e]], 1);
    }
}

// ---------------- scan blocks + fused dinv ----------------
__global__ void scan_blocks(const int* __restrict__ deg, int* __restrict__ row_ptr,
                            int* __restrict__ block_tot, float* __restrict__ dinv) {
    __shared__ int sd[256];
    int t = threadIdx.x;
    int idx = blockIdx.x * 256 + t;
    int v = (idx < N_NODES) ? deg[idx] : 0;
    if (idx < N_NODES) dinv[idx] = rsqrtf((float)(v + 1));   // +1 self-loop
    sd[t] = v;
    __syncthreads();
    for (int off = 1; off < 256; off <<= 1) {
        int a = (t >= off) ? sd[t - off] : 0;
        __syncthreads();
        sd[t] += a;
        __syncthreads();
    }
    if (idx < N_NODES) row_ptr[idx] = sd[t] - v;
    if (t == 255) block_tot[blockIdx.x] = sd[255];
}

__global__ void scan_totals(int* block_tot) {
    __shared__ int sd[256];
    int t = threadIdx.x;
    int v = (t < SCAN_NB) ? block_tot[t] : 0;
    sd[t] = v;
    __syncthreads();
    for (int off = 1; off < 256; off <<= 1) {
        int a = (t >= off) ? sd[t - off] : 0;
        __syncthreads();
        sd[t] += a;
        __syncthreads();
    }
    if (t < SCAN_NB) block_tot[t] = sd[t] - v;
}

__global__ void add_offsets(int* __restrict__ row_ptr, const int* __restrict__ block_tot) {
    int idx = blockIdx.x * 256 + threadIdx.x;
    if (idx < N_NODES) row_ptr[idx] += block_tot[blockIdx.x];
    if (idx == 0) row_ptr[N_NODES] = N_EDGES;
}

// ---------------- bucket edges into CSR order; combined 8B record ----------------
// erec[pos] = { float bits of norm (dinv[s]*dinv[d]), src index }
__global__ void bucket_edges(const int* __restrict__ src, const int* __restrict__ dst,
                             const float* __restrict__ dinv,
                             const int* __restrict__ row_ptr, int* __restrict__ cursor,
                             uint2v* __restrict__ erec) {
    int e = blockIdx.x * blockDim.x + threadIdx.x;
    if (e < N_EDGES) {
        int d = dst[e];
        int s = src[e];
        int pos = row_ptr[d] + atomicAdd(&cursor[d], 1);
        uint2v r;
        r.x = __float_as_uint(dinv[s] * dinv[d]);
        r.y = (unsigned)s;
        erec[pos] = r;
    }
}

// ---------------- split-bf16 MFMA GEMM, fp32 A, split ONCE at staging ----------------
// hbf[M,256] = bf16( A[M,256] @ W[256,256] ); A fp32 row-major, W transposed hi/lo bf16.
// BM=64, BN=256 (single col-block): A read from HBM exactly once.
// A staged as hi/lo short8 rows (stride 32 shorts) — round-8-proven LDS layout.
#define BM 64
#define BK 32
__global__ __launch_bounds__(256) void gemm_mfma(
        const float* __restrict__ A,
        const short* __restrict__ Bthi, const short* __restrict__ Btlo,
        ushort_t* __restrict__ hbf, int M) {
    __shared__ short sAh[BM * BK], sAl[BM * BK];       // 4KB + 4KB
    __shared__ short sBh[256 * BK], sBl[256 * BK];     // 16KB + 16KB
    int tid = threadIdx.x;
    int wave = tid >> 6, lane = tid & 63;
    int q = lane >> 4, t = lane & 15;
    int row0 = blockIdx.x * BM;
    int wc = wave * 64;            // wave's 64-col slice of N=256

    int lrow = lane >> 2;          // 0..15 (B staging)
    int lk = (lane & 3) * 8;       // k offset (shorts)
    int ar = tid >> 2;             // A staging: row 0..63
    int ak = (tid & 3) * 8;        // A staging: 8 floats at kt+ak

    float4v acc[4][4] = {};
    for (int kt = 0; kt < 256; kt += BK) {
        // ---- A tile: global fp32 -> regs ----
        int ga = row0 + ar; if (ga >= M) ga = M - 1;   // clamp; never stored
        const float* ap = &A[(size_t)ga * 256 + kt + ak];
        float4 a0 = *(const float4*)ap;
        float4 a1 = *(const float4*)(ap + 4);
        // ---- B tile: async global->LDS ----
#pragma unroll
        for (int j = 0; j < 4; ++j) {
            int n = wave * 64 + j * 16 + lrow;
            size_t boff = (size_t)n * 256 + kt + lk;
            int ldso = wave * 2048 + j * 512 + lane * 8;
            gld_lds16(&Bthi[boff], &sBh[ldso]);
            gld_lds16(&Btlo[boff], &sBl[ldso]);
        }
        // ---- split once, write short8 hi/lo to LDS (round-8 layout) ----
        {
            short8 h, l;
            unsigned short hh;
            hh = f2bf(a0.x); h[0] = (short)hh; l[0] = (short)f2bf(a0.x - bf2f(hh));
            hh = f2bf(a0.y); h[1] = (short)hh; l[1] = (short)f2bf(a0.y - bf2f(hh));
            hh = f2bf(a0.z); h[2] = (short)hh; l[2] = (short)f2bf(a0.z - bf2f(hh));
            hh = f2bf(a0.w); h[3] = (short)hh; l[3] = (short)f2bf(a0.w - bf2f(hh));
            hh = f2bf(a1.x); h[4] = (short)hh; l[4] = (short)f2bf(a1.x - bf2f(hh));
            hh = f2bf(a1.y); h[5] = (short)hh; l[5] = (short)f2bf(a1.y - bf2f(hh));
            hh = f2bf(a1.z); h[6] = (short)hh; l[6] = (short)f2bf(a1.z - bf2f(hh));
            hh = f2bf(a1.w); h[7] = (short)hh; l[7] = (short)f2bf(a1.w - bf2f(hh));
            *(short8*)&sAh[ar * BK + ak] = h;
            *(short8*)&sAl[ar * BK + ak] = l;
        }
        __syncthreads();
        // ---- fragments (identical to round-8 path) ----
        short8 ah[4], al[4], bh[4], bl[4];
#pragma unroll
        for (int mi = 0; mi < 4; ++mi) {
            int r = mi * 16 + t;
            ah[mi] = *(const short8*)&sAh[r * BK + q * 8];
            al[mi] = *(const short8*)&sAl[r * BK + q * 8];
        }
#pragma unroll
        for (int ni = 0; ni < 4; ++ni) {
            int n = wc + ni * 16 + t;
            bh[ni] = *(const short8*)&sBh[n * BK + q * 8];
            bl[ni] = *(const short8*)&sBl[n * BK + q * 8];
        }
#pragma unroll
        for (int mi = 0; mi < 4; ++mi)
#pragma unroll
            for (int ni = 0; ni < 4; ++ni) {
                acc[mi][ni] = __builtin_amdgcn_mfma_f32_16x16x32_bf16(ah[mi], bh[ni], acc[mi][ni], 0, 0, 0);
                acc[mi][ni] = __builtin_amdgcn_mfma_f32_16x16x32_bf16(ah[mi], bl[ni], acc[mi][ni], 0, 0, 0);
                acc[mi][ni] = __builtin_amdgcn_mfma_f32_16x16x32_bf16(al[mi], bh[ni], acc[mi][ni], 0, 0, 0);
            }
        __syncthreads();
    }
#pragma unroll
    for (int mi = 0; mi < 4; ++mi) {
        int gr0 = row0 + mi * 16 + q * 4;
#pragma unroll
        for (int rr = 0; rr < 4; ++rr) {
            int gr = gr0 + rr;
            if (gr < M) {
#pragma unroll
                for (int ni = 0; ni < 4; ++ni)
                    hbf[(size_t)gr * 256 + wc + ni * 16 + t] = f2bf(acc[mi][ni][rr]);
            }
        }
    }
}

// -------- CSR gather over bf16 h; 2 edges per wave-iteration; fused epilogue --------
// wave = node; half-wave (32 lanes x ushort8 = 512B) covers one full row.
// OUTBF16: write bf16 (feeds pooling); else fp32 (feeds gemm2, which splits on the fly).
template<bool OUTBF16>
__global__ __launch_bounds__(256) void gather_bf16(
        const int* __restrict__ row_ptr, const uint2v* __restrict__ erec,
        const float* __restrict__ dinv,
        const ushort_t* __restrict__ hbf, const float* __restrict__ b,
        float* __restrict__ outF, ushort_t* __restrict__ outBf) {
    int wave = threadIdx.x >> 6;
    int node = blockIdx.x * 4 + wave;      // N_NODES % 4 == 0
    int lane = threadIdx.x & 63;
    int g = lane >> 5;                      // half-wave: which of the 2 edges
    int hl = lane & 31;                     // feats hl*8 .. hl*8+7
    int beg = row_ptr[node], end = row_ptr[node + 1];
    float dd = dinv[node];
    float acc[8] = {};
    for (int cbeg = beg; cbeg < end; cbeg += 64) {
        int n = end - cbeg; if (n > 64) n = 64;
        uint2v er = {0u, 0u};
        if (lane < n) er = __builtin_nontemporal_load(&erec[cbeg + lane]);
        int sv = (int)er.y;
        float wv = __uint_as_float(er.x);
        for (int k = 0; k < n; k += 2) {
            int idx = k + g;                // <= 63 always; w==0 if idx>=n
            int s = __shfl(sv, idx);
            float w = __shfl(wv, idx);
            ushort8 hv = *(const ushort8*)&hbf[(size_t)s * 256 + hl * 8];
#pragma unroll
            for (int j = 0; j < 8; ++j)
                acc[j] = fmaf(bf2f(hv[j]), w, acc[j]);
        }
    }
    // combine the two half-waves
#pragma unroll
    for (int j = 0; j < 8; ++j) acc[j] += __shfl_xor(acc[j], 32);
    if (g == 0) {
        ushort8 sf = *(const ushort8*)&hbf[(size_t)node * 256 + hl * 8];
        float ws = dd * dd;
#pragma unroll
        for (int j = 0; j < 8; ++j)
            acc[j] = fmaxf(fmaf(bf2f(sf[j]), ws, acc[j]) + b[hl * 8 + j], 0.f);
        size_t o = (size_t)node * 256 + hl * 8;
        if (OUTBF16) {
            ushort8 hb;
#pragma unroll
            for (int j = 0; j < 8; ++j) hb[j] = f2bf(acc[j]);
            *(ushort8*)&outBf[o] = hb;
        } else {
            float4 v0 = make_float4(acc[0], acc[1], acc[2], acc[3]);
            float4 v1 = make_float4(acc[4], acc[5], acc[6], acc[7]);
            *(float4*)&outF[o] = v0;
            *(float4*)&outF[o + 4] = v1;
        }
    }
}

// ---------------- parallel triple pooling over bf16 h (1 wave/block) ----------------
__global__ __launch_bounds__(64) void pool_partial(
        const ushort_t* __restrict__ h, const int* __restrict__ batch,
        float* __restrict__ psum, int* __restrict__ pmaxi) {
    int g = blockIdx.x;
    int chunk = blockIdx.y;
    int lane = threadIdx.x;  // 64; lane covers feats lane*4..lane*4+3
    int lo = 0, hi = N_NODES;
    while (lo < hi) { int mid = (lo + hi) >> 1; if (batch[mid] < g) lo = mid + 1; else hi = mid; }
    int start = lo;
    lo = 0; hi = N_NODES;
    while (lo < hi) { int mid = (lo + hi) >> 1; if (batch[mid] < g + 1) lo = mid + 1; else hi = mid; }
    int end = lo;
    int len = end - start;
    if (len <= 0) return;
    int per = (len + POOL_CHUNKS - 1) / POOL_CHUNKS;
    int cs = start + chunk * per;
    int ce = cs + per; if (ce > end) ce = end;
    if (cs >= ce) return;
    float4 sum = make_float4(0.f, 0.f, 0.f, 0.f);
    float4 mx  = make_float4(0.f, 0.f, 0.f, 0.f);
    for (int n = cs; n < ce; ++n) {
        ushort4v u = *(const ushort4v*)&h[(size_t)n * 256 + lane * 4];
        float vx = bf2f(u.x), vy = bf2f(u.y), vz = bf2f(u.z), vw = bf2f(u.w);
        sum.x += vx; sum.y += vy; sum.z += vz; sum.w += vw;
        mx.x = fmaxf(mx.x, vx); mx.y = fmaxf(mx.y, vy);
        mx.z = fmaxf(mx.z, vz); mx.w = fmaxf(mx.w, vw);
    }
    float* ps = &psum[g * F + lane * 4];
    atomicAdd(&ps[0], sum.x); atomicAdd(&ps[1], sum.y);
    atomicAdd(&ps[2], sum.z); atomicAdd(&ps[3], sum.w);
    int* pm = &pmaxi[g * F + lane * 4];
    atomicMax(&pm[0], __float_as_int(mx.x)); atomicMax(&pm[1], __float_as_int(mx.y));
    atomicMax(&pm[2], __float_as_int(mx.z)); atomicMax(&pm[3], __float_as_int(mx.w));
}

// ---------------- final GEMM: out[64,128] = [mean|max|sum] @ Wfc + bfc ----------------
__global__ void final_gemm(const float* __restrict__ psum, const int* __restrict__ pmaxi,
                           const int* __restrict__ batch,
                           const float* __restrict__ Wfc, const float* __restrict__ bfc,
                           float* __restrict__ out) {
    int g = blockIdx.x;   // 64
    int o = threadIdx.x;  // 128
    __shared__ float row[G_DIM];
    __shared__ int s_cnt;
    if (threadIdx.x == 0) {
        int lo = 0, hi = N_NODES;
        while (lo < hi) { int mid = (lo + hi) >> 1; if (batch[mid] < g) lo = mid + 1; else hi = mid; }
        int start = lo;
        lo = 0; hi = N_NODES;
        while (lo < hi) { int mid = (lo + hi) >> 1; if (batch[mid] < g + 1) lo = mid + 1; else hi = mid; }
        s_cnt = lo - start;
    }
    __syncthreads();
    float inv = 1.0f / fmaxf((float)s_cnt, 1.0f);
    for (int i = threadIdx.x; i < F; i += 128) {
        float s = psum[g * F + i];
        row[i]       = s * inv;
        row[F + i]   = __int_as_float(pmaxi[g * F + i]);
        row[2*F + i] = s;
    }
    __syncthreads();
    float acc = bfc[o];
    for (int k = 0; k < G_DIM; ++k) acc += row[k] * Wfc[k * F_OUT + o];
    out[g * F_OUT + o] = acc;
}

extern "C" void kernel_launch(void* const* d_in, const int* in_sizes, int n_in,
                              void* d_out, int out_size, void* d_ws, size_t ws_size,
                              hipStream_t stream) {
    const float* x    = (const float*)d_in[0];
    const int*   ei   = (const int*)d_in[1];
    const int*   batch= (const int*)d_in[2];
    const float* W1   = (const float*)d_in[4];
    const float* b1   = (const float*)d_in[5];
    const float* W2   = (const float*)d_in[6];
    const float* b2   = (const float*)d_in[7];
    const float* Wfc  = (const float*)d_in[8];
    const float* bfc  = (const float*)d_in[9];
    float* out = (float*)d_out;

    const int* src = ei;
    const int* dst = ei + N_EDGES;

    const size_t NF = (size_t)N_NODES * F;   // 12.8M

    ushort_t* hbf = (ushort_t*)d_ws;         // [N,256] bf16 gemm out (25.6 MB)
    float* h1    = (float*)(hbf + NF);       // [N,256] fp32 gather1 out (51.2 MB)
    ushort_t* h2bf = (ushort_t*)h1;          // alias: gather2 bf16 out reuses h1 region
    short* w1hi  = (short*)(h1 + NF);        // 4x 64K shorts
    short* w1lo  = w1hi + 65536;
    short* w2hi  = w1lo + 65536;
    short* w2lo  = w2hi + 65536;
    float* dinv  = (float*)(w2lo + 65536);   // [N]
    int*   deg   = (int*)(dinv + N_NODES);   // [N]
    int*   cursor= deg + N_NODES;            // [N]
    int*   row_ptr = cursor + N_NODES;       // [N+1]
    int*   btot  = row_ptr + N_NODES + 1;    // [256]
    uint2v* erec = (uint2v*)(btot + 256);    // [E] 8B records (6.4 MB)
    float* psum  = (float*)(erec + N_EDGES); // [64][256]
    int*   pmaxi = (int*)(psum + N_GRAPHS * F);  // [64][256]

    // ---- degree + norm + CSR (+ W casts fused) ----
    hipMemsetAsync(deg, 0, 2 * N_NODES * sizeof(int), stream);   // deg + cursor
    prep_w_deg<<<512 + (N_EDGES + 255) / 256, 256, 0, stream>>>(
        W1, W2, w1hi, w1lo, w2hi, w2lo, dst, deg);
    scan_blocks<<<SCAN_NB, 256, 0, stream>>>(deg, row_ptr, btot, dinv);
    scan_totals<<<1, 256, 0, stream>>>(btot);
    add_offsets<<<SCAN_NB, 256, 0, stream>>>(row_ptr, btot);
    bucket_edges<<<(N_EDGES + 255) / 256, 256, 0, stream>>>(src, dst, dinv, row_ptr,
                                                            cursor, erec);

    int ggemm = (N_NODES + BM - 1) / BM;      // 782
    int ngb = N_NODES / 4;                    // 12500 blocks of 4 waves

    // ---- layer 1 ----
    gemm_mfma<<<ggemm, 256, 0, stream>>>(x, w1hi, w1lo, hbf, N_NODES);
    gather_bf16<false><<<ngb, 256, 0, stream>>>(row_ptr, erec, dinv, hbf, b1,
                                                h1, nullptr);    // h1 fp32

    // ---- layer 2 ----
    gemm_mfma<<<ggemm, 256, 0, stream>>>(h1, w2hi, w2lo, hbf, N_NODES);
    gather_bf16<true><<<ngb, 256, 0, stream>>>(row_ptr, erec, dinv, hbf, b2,
                                               nullptr, h2bf);   // h2 bf16

    // ---- pooling + classifier ----
    hipMemsetAsync(psum, 0, N_GRAPHS * F * 2 * sizeof(float), stream);
    pool_partial<<<dim3(N_GRAPHS, POOL_CHUNKS), 64, 0, stream>>>(h2bf, batch, psum, pmaxi);
    final_gemm<<<N_GRAPHS, F_OUT, 0, stream>>>(psum, pmaxi, batch, Wfc, bfc, out);
}

// Round 12
// 422.198 us; speedup vs baseline: 1.1253x; 1.0194x over previous
//
#include <hip/hip_runtime.h>

#define N_NODES 50000
#define N_EDGES 800000
#define N_GRAPHS 64
#define F 256        // F_IN == F_HID
#define F_OUT 128
#define G_DIM 768    // 3*F
#define SCAN_NB ((N_NODES + 255) / 256)   // 196
#define POOL_CHUNKS 16

typedef unsigned short ushort_t;
typedef short short8 __attribute__((ext_vector_type(8)));
typedef short short4v __attribute__((ext_vector_type(4)));
typedef unsigned short ushort8 __attribute__((ext_vector_type(8)));
typedef unsigned short ushort4v __attribute__((ext_vector_type(4)));
typedef float float4v __attribute__((ext_vector_type(4)));
typedef unsigned int uint2v __attribute__((ext_vector_type(2)));

// ---- bf16 helpers (RNE) ----
__device__ __forceinline__ unsigned short f2bf(float f) {
    unsigned int u = __float_as_uint(f);
    u += 0x7FFFu + ((u >> 16) & 1u);
    return (unsigned short)(u >> 16);
}
__device__ __forceinline__ float bf2f(unsigned short s) {
    return __uint_as_float(((unsigned int)s) << 16);
}

// ---- async global->LDS, 16B per lane; LDS dest = wave-uniform base + lane*16 ----
__device__ __forceinline__ void gld_lds16(const void* gsrc, void* ldst) {
    __builtin_amdgcn_global_load_lds(
        (const __attribute__((address_space(1))) unsigned int*)gsrc,
        (__attribute__((address_space(3))) unsigned int*)ldst, 16, 0, 0);
}

// ---------------- fused: W1/W2 transposed hi/lo cast (blocks 0..511) + degree count ----------------
__global__ void prep_w_deg(const float* __restrict__ W1, const float* __restrict__ W2,
                           short* __restrict__ hi1, short* __restrict__ lo1,
                           short* __restrict__ hi2, short* __restrict__ lo2,
                           const int* __restrict__ dst, int* __restrict__ deg) {
    int blk = blockIdx.x;
    if (blk < 512) {
        const float* W = (blk < 256) ? W1 : W2;
        short* hi = (blk < 256) ? hi1 : hi2;
        short* lo = (blk < 256) ? lo1 : lo2;
        int n = blk & 255;
        int k = threadIdx.x;
        float v = W[k * 256 + n];
        unsigned short h = f2bf(v);
        hi[n * 256 + k] = (short)h;
        lo[n * 256 + k] = (short)f2bf(v - bf2f(h));
    } else {
        int e = (blk - 512) * 256 + threadIdx.x;
        if (e < N_EDGES) atomicAdd(&deg[dst[e]], 1);
    }
}

// ---------------- scan blocks + fused dinv ----------------
__global__ void scan_blocks(const int* __restrict__ deg, int* __restrict__ row_ptr,
                            int* __restrict__ block_tot, float* __restrict__ dinv) {
    __shared__ int sd[256];
    int t = threadIdx.x;
    int idx = blockIdx.x * 256 + t;
    int v = (idx < N_NODES) ? deg[idx] : 0;
    if (idx < N_NODES) dinv[idx] = rsqrtf((float)(v + 1));   // +1 self-loop
    sd[t] = v;
    __syncthreads();
    for (int off = 1; off < 256; off <<= 1) {
        int a = (t >= off) ? sd[t - off] : 0;
        __syncthreads();
        sd[t] += a;
        __syncthreads();
    }
    if (idx < N_NODES) row_ptr[idx] = sd[t] - v;
    if (t == 255) block_tot[blockIdx.x] = sd[255];
}

__global__ void scan_totals(int* block_tot) {
    __shared__ int sd[256];
    int t = threadIdx.x;
    int v = (t < SCAN_NB) ? block_tot[t] : 0;
    sd[t] = v;
    __syncthreads();
    for (int off = 1; off < 256; off <<= 1) {
        int a = (t >= off) ? sd[t - off] : 0;
        __syncthreads();
        sd[t] += a;
        __syncthreads();
    }
    if (t < SCAN_NB) block_tot[t] = sd[t] - v;
}

__global__ void add_offsets(int* __restrict__ row_ptr, const int* __restrict__ block_tot) {
    int idx = blockIdx.x * 256 + threadIdx.x;
    if (idx < N_NODES) row_ptr[idx] += block_tot[blockIdx.x];
    if (idx == 0) row_ptr[N_NODES] = N_EDGES;
}

// ---------------- bucket edges into CSR order; combined 8B record ----------------
// erec[pos] = { float bits of norm (dinv[s]*dinv[d]), src index }
__global__ void bucket_edges(const int* __restrict__ src, const int* __restrict__ dst,
                             const float* __restrict__ dinv,
                             const int* __restrict__ row_ptr, int* __restrict__ cursor,
                             uint2v* __restrict__ erec) {
    int e = blockIdx.x * blockDim.x + threadIdx.x;
    if (e < N_EDGES) {
        int d = dst[e];
        int s = src[e];
        int pos = row_ptr[d] + atomicAdd(&cursor[d], 1);
        uint2v r;
        r.x = __float_as_uint(dinv[s] * dinv[d]);
        r.y = (unsigned)s;
        erec[pos] = r;
    }
}

// ---------------- GEMM1: split-bf16 MFMA, fp32 A, split ONCE at staging ----------------
// hbf[M,256] = bf16( A[M,256] @ W[256,256] ); A fp32 row-major, W transposed hi/lo bf16.
#define BM 64
#define BK 32
__global__ __launch_bounds__(256) void gemm_mfma(
        const float* __restrict__ A,
        const short* __restrict__ Bthi, const short* __restrict__ Btlo,
        ushort_t* __restrict__ hbf, int M) {
    __shared__ short sAh[BM * BK], sAl[BM * BK];       // 4KB + 4KB
    __shared__ short sBh[256 * BK], sBl[256 * BK];     // 16KB + 16KB
    int tid = threadIdx.x;
    int wave = tid >> 6, lane = tid & 63;
    int q = lane >> 4, t = lane & 15;
    int row0 = blockIdx.x * BM;
    int wc = wave * 64;            // wave's 64-col slice of N=256

    int lrow = lane >> 2;          // 0..15 (B staging)
    int lk = (lane & 3) * 8;       // k offset (shorts)
    int ar = tid >> 2;             // A staging: row 0..63
    int ak = (tid & 3) * 8;        // A staging: 8 floats at kt+ak

    float4v acc[4][4] = {};
    for (int kt = 0; kt < 256; kt += BK) {
        // ---- A tile: global fp32 -> regs ----
        int ga = row0 + ar; if (ga >= M) ga = M - 1;   // clamp; never stored
        const float* ap = &A[(size_t)ga * 256 + kt + ak];
        float4 a0 = *(const float4*)ap;
        float4 a1 = *(const float4*)(ap + 4);
        // ---- B tile: async global->LDS ----
#pragma unroll
        for (int j = 0; j < 4; ++j) {
            int n = wave * 64 + j * 16 + lrow;
            size_t boff = (size_t)n * 256 + kt + lk;
            int ldso = wave * 2048 + j * 512 + lane * 8;
            gld_lds16(&Bthi[boff], &sBh[ldso]);
            gld_lds16(&Btlo[boff], &sBl[ldso]);
        }
        // ---- split once, write short8 hi/lo to LDS ----
        {
            short8 h, l;
            unsigned short hh;
            hh = f2bf(a0.x); h[0] = (short)hh; l[0] = (short)f2bf(a0.x - bf2f(hh));
            hh = f2bf(a0.y); h[1] = (short)hh; l[1] = (short)f2bf(a0.y - bf2f(hh));
            hh = f2bf(a0.z); h[2] = (short)hh; l[2] = (short)f2bf(a0.z - bf2f(hh));
            hh = f2bf(a0.w); h[3] = (short)hh; l[3] = (short)f2bf(a0.w - bf2f(hh));
            hh = f2bf(a1.x); h[4] = (short)hh; l[4] = (short)f2bf(a1.x - bf2f(hh));
            hh = f2bf(a1.y); h[5] = (short)hh; l[5] = (short)f2bf(a1.y - bf2f(hh));
            hh = f2bf(a1.z); h[6] = (short)hh; l[6] = (short)f2bf(a1.z - bf2f(hh));
            hh = f2bf(a1.w); h[7] = (short)hh; l[7] = (short)f2bf(a1.w - bf2f(hh));
            *(short8*)&sAh[ar * BK + ak] = h;
            *(short8*)&sAl[ar * BK + ak] = l;
        }
        __syncthreads();
        short8 ah[4], al[4], bh[4], bl[4];
#pragma unroll
        for (int mi = 0; mi < 4; ++mi) {
            int r = mi * 16 + t;
            ah[mi] = *(const short8*)&sAh[r * BK + q * 8];
            al[mi] = *(const short8*)&sAl[r * BK + q * 8];
        }
#pragma unroll
        for (int ni = 0; ni < 4; ++ni) {
            int n = wc + ni * 16 + t;
            bh[ni] = *(const short8*)&sBh[n * BK + q * 8];
            bl[ni] = *(const short8*)&sBl[n * BK + q * 8];
        }
#pragma unroll
        for (int mi = 0; mi < 4; ++mi)
#pragma unroll
            for (int ni = 0; ni < 4; ++ni) {
                acc[mi][ni] = __builtin_amdgcn_mfma_f32_16x16x32_bf16(ah[mi], bh[ni], acc[mi][ni], 0, 0, 0);
                acc[mi][ni] = __builtin_amdgcn_mfma_f32_16x16x32_bf16(ah[mi], bl[ni], acc[mi][ni], 0, 0, 0);
                acc[mi][ni] = __builtin_amdgcn_mfma_f32_16x16x32_bf16(al[mi], bh[ni], acc[mi][ni], 0, 0, 0);
            }
        __syncthreads();
    }
#pragma unroll
    for (int mi = 0; mi < 4; ++mi) {
        int gr0 = row0 + mi * 16 + q * 4;
#pragma unroll
        for (int rr = 0; rr < 4; ++rr) {
            int gr = gr0 + rr;
            if (gr < M) {
#pragma unroll
                for (int ni = 0; ni < 4; ++ni)
                    hbf[(size_t)gr * 256 + wc + ni * 16 + t] = f2bf(acc[mi][ni][rr]);
            }
        }
    }
}

// ---------------- GEMM2: bf16 A (direct async staging), W hi/lo -> 2 MFMAs ----------------
__global__ __launch_bounds__(256) void gemm_mfma_bf16(
        const ushort_t* __restrict__ A,   // [M,256] bf16
        const short* __restrict__ Bthi, const short* __restrict__ Btlo,
        ushort_t* __restrict__ hbf, int M) {
    __shared__ short sA[BM * BK];                      // 4KB
    __shared__ short sBh[256 * BK], sBl[256 * BK];     // 16KB + 16KB
    int tid = threadIdx.x;
    int wave = tid >> 6, lane = tid & 63;
    int q = lane >> 4, t = lane & 15;
    int row0 = blockIdx.x * BM;
    int wc = wave * 64;

    int lrow = lane >> 2;          // 0..15 (B staging)
    int lk = (lane & 3) * 8;       // k offset (shorts)
    int ar = tid >> 2;             // A staging: row 0..63
    int ak = (tid & 3) * 8;        // 8 shorts at kt+ak

    float4v acc[4][4] = {};
    for (int kt = 0; kt < 256; kt += BK) {
        // A: one 16B async stage per thread (LDS addr = tid*16B = wave-uniform + lane*16)
        {
            int ga = row0 + ar; if (ga >= M) ga = M - 1;
            gld_lds16(&A[(size_t)ga * 256 + kt + ak], &sA[ar * BK + ak]);
        }
#pragma unroll
        for (int j = 0; j < 4; ++j) {
            int n = wave * 64 + j * 16 + lrow;
            size_t boff = (size_t)n * 256 + kt + lk;
            int ldso = wave * 2048 + j * 512 + lane * 8;
            gld_lds16(&Bthi[boff], &sBh[ldso]);
            gld_lds16(&Btlo[boff], &sBl[ldso]);
        }
        __syncthreads();
        short8 ah[4], bh[4], bl[4];
#pragma unroll
        for (int mi = 0; mi < 4; ++mi) {
            int r = mi * 16 + t;
            ah[mi] = *(const short8*)&sA[r * BK + q * 8];
        }
#pragma unroll
        for (int ni = 0; ni < 4; ++ni) {
            int n = wc + ni * 16 + t;
            bh[ni] = *(const short8*)&sBh[n * BK + q * 8];
            bl[ni] = *(const short8*)&sBl[n * BK + q * 8];
        }
#pragma unroll
        for (int mi = 0; mi < 4; ++mi)
#pragma unroll
            for (int ni = 0; ni < 4; ++ni) {
                acc[mi][ni] = __builtin_amdgcn_mfma_f32_16x16x32_bf16(ah[mi], bh[ni], acc[mi][ni], 0, 0, 0);
                acc[mi][ni] = __builtin_amdgcn_mfma_f32_16x16x32_bf16(ah[mi], bl[ni], acc[mi][ni], 0, 0, 0);
            }
        __syncthreads();
    }
#pragma unroll
    for (int mi = 0; mi < 4; ++mi) {
        int gr0 = row0 + mi * 16 + q * 4;
#pragma unroll
        for (int rr = 0; rr < 4; ++rr) {
            int gr = gr0 + rr;
            if (gr < M) {
#pragma unroll
                for (int ni = 0; ni < 4; ++ni)
                    hbf[(size_t)gr * 256 + wc + ni * 16 + t] = f2bf(acc[mi][ni][rr]);
            }
        }
    }
}

// -------- CSR gather over bf16 h; 2 edges per wave-iteration; fused epilogue; bf16 out --------
__global__ __launch_bounds__(256) void gather_bf16(
        const int* __restrict__ row_ptr, const uint2v* __restrict__ erec,
        const float* __restrict__ dinv,
        const ushort_t* __restrict__ hbf, const float* __restrict__ b,
        ushort_t* __restrict__ outBf) {
    int wave = threadIdx.x >> 6;
    int node = blockIdx.x * 4 + wave;      // N_NODES % 4 == 0
    int lane = threadIdx.x & 63;
    int g = lane >> 5;                      // half-wave: which of the 2 edges
    int hl = lane & 31;                     // feats hl*8 .. hl*8+7
    int beg = row_ptr[node], end = row_ptr[node + 1];
    float dd = dinv[node];
    float acc[8] = {};
    for (int cbeg = beg; cbeg < end; cbeg += 64) {
        int n = end - cbeg; if (n > 64) n = 64;
        uint2v er = {0u, 0u};
        if (lane < n) er = __builtin_nontemporal_load(&erec[cbeg + lane]);
        int sv = (int)er.y;
        float wv = __uint_as_float(er.x);
        for (int k = 0; k < n; k += 2) {
            int idx = k + g;                // <= 63 always; w==0 if idx>=n
            int s = __shfl(sv, idx);
            float w = __shfl(wv, idx);
            ushort8 hv = *(const ushort8*)&hbf[(size_t)s * 256 + hl * 8];
#pragma unroll
            for (int j = 0; j < 8; ++j)
                acc[j] = fmaf(bf2f(hv[j]), w, acc[j]);
        }
    }
#pragma unroll
    for (int j = 0; j < 8; ++j) acc[j] += __shfl_xor(acc[j], 32);
    if (g == 0) {
        ushort8 sf = *(const ushort8*)&hbf[(size_t)node * 256 + hl * 8];
        float ws = dd * dd;
        ushort8 hb;
#pragma unroll
        for (int j = 0; j < 8; ++j) {
            float v = fmaxf(fmaf(bf2f(sf[j]), ws, acc[j]) + b[hl * 8 + j], 0.f);
            hb[j] = f2bf(v);
        }
        *(ushort8*)&outBf[(size_t)node * 256 + hl * 8] = hb;
    }
}

// ---------------- parallel triple pooling over bf16 h (1 wave/block) ----------------
__global__ __launch_bounds__(64) void pool_partial(
        const ushort_t* __restrict__ h, const int* __restrict__ batch,
        float* __restrict__ psum, int* __restrict__ pmaxi) {
    int g = blockIdx.x;
    int chunk = blockIdx.y;
    int lane = threadIdx.x;  // 64; lane covers feats lane*4..lane*4+3
    int lo = 0, hi = N_NODES;
    while (lo < hi) { int mid = (lo + hi) >> 1; if (batch[mid] < g) lo = mid + 1; else hi = mid; }
    int start = lo;
    lo = 0; hi = N_NODES;
    while (lo < hi) { int mid = (lo + hi) >> 1; if (batch[mid] < g + 1) lo = mid + 1; else hi = mid; }
    int end = lo;
    int len = end - start;
    if (len <= 0) return;
    int per = (len + POOL_CHUNKS - 1) / POOL_CHUNKS;
    int cs = start + chunk * per;
    int ce = cs + per; if (ce > end) ce = end;
    if (cs >= ce) return;
    float4 sum = make_float4(0.f, 0.f, 0.f, 0.f);
    float4 mx  = make_float4(0.f, 0.f, 0.f, 0.f);
    for (int n = cs; n < ce; ++n) {
        ushort4v u = *(const ushort4v*)&h[(size_t)n * 256 + lane * 4];
        float vx = bf2f(u.x), vy = bf2f(u.y), vz = bf2f(u.z), vw = bf2f(u.w);
        sum.x += vx; sum.y += vy; sum.z += vz; sum.w += vw;
        mx.x = fmaxf(mx.x, vx); mx.y = fmaxf(mx.y, vy);
        mx.z = fmaxf(mx.z, vz); mx.w = fmaxf(mx.w, vw);
    }
    float* ps = &psum[g * F + lane * 4];
    atomicAdd(&ps[0], sum.x); atomicAdd(&ps[1], sum.y);
    atomicAdd(&ps[2], sum.z); atomicAdd(&ps[3], sum.w);
    int* pm = &pmaxi[g * F + lane * 4];
    atomicMax(&pm[0], __float_as_int(mx.x)); atomicMax(&pm[1], __float_as_int(mx.y));
    atomicMax(&pm[2], __float_as_int(mx.z)); atomicMax(&pm[3], __float_as_int(mx.w));
}

// ---------------- final GEMM: out[64,128] = [mean|max|sum] @ Wfc + bfc ----------------
__global__ void final_gemm(const float* __restrict__ psum, const int* __restrict__ pmaxi,
                           const int* __restrict__ batch,
                           const float* __restrict__ Wfc, const float* __restrict__ bfc,
                           float* __restrict__ out) {
    int g = blockIdx.x;   // 64
    int o = threadIdx.x;  // 128
    __shared__ float row[G_DIM];
    __shared__ int s_cnt;
    if (threadIdx.x == 0) {
        int lo = 0, hi = N_NODES;
        while (lo < hi) { int mid = (lo + hi) >> 1; if (batch[mid] < g) lo = mid + 1; else hi = mid; }
        int start = lo;
        lo = 0; hi = N_NODES;
        while (lo < hi) { int mid = (lo + hi) >> 1; if (batch[mid] < g + 1) lo = mid + 1; else hi = mid; }
        s_cnt = lo - start;
    }
    __syncthreads();
    float inv = 1.0f / fmaxf((float)s_cnt, 1.0f);
    for (int i = threadIdx.x; i < F; i += 128) {
        float s = psum[g * F + i];
        row[i]       = s * inv;
        row[F + i]   = __int_as_float(pmaxi[g * F + i]);
        row[2*F + i] = s;
    }
    __syncthreads();
    float acc = bfc[o];
    for (int k = 0; k < G_DIM; ++k) acc += row[k] * Wfc[k * F_OUT + o];
    out[g * F_OUT + o] = acc;
}

extern "C" void kernel_launch(void* const* d_in, const int* in_sizes, int n_in,
                              void* d_out, int out_size, void* d_ws, size_t ws_size,
                              hipStream_t stream) {
    const float* x    = (const float*)d_in[0];
    const int*   ei   = (const int*)d_in[1];
    const int*   batch= (const int*)d_in[2];
    const float* W1   = (const float*)d_in[4];
    const float* b1   = (const float*)d_in[5];
    const float* W2   = (const float*)d_in[6];
    const float* b2   = (const float*)d_in[7];
    const float* Wfc  = (const float*)d_in[8];
    const float* bfc  = (const float*)d_in[9];
    float* out = (float*)d_out;

    const int* src = ei;
    const int* dst = ei + N_EDGES;

    const size_t NF = (size_t)N_NODES * F;   // 12.8M

    ushort_t* hbf  = (ushort_t*)d_ws;        // [N,256] bf16 gemm out (25.6 MB)
    ushort_t* h1bf = hbf + NF;               // [N,256] bf16 gather1 out; reused as h2bf
    ushort_t* h2bf = h1bf;                   //   (h1 consumed by gemm2 before gather2 writes)
    short* w1hi  = (short*)(h1bf + NF);      // 4x 64K shorts
    short* w1lo  = w1hi + 65536;
    short* w2hi  = w1lo + 65536;
    short* w2lo  = w2hi + 65536;
    float* dinv  = (float*)(w2lo + 65536);   // [N]
    // ---- contiguous zero-init region: deg, cursor, psum, pmaxi ----
    int*   deg   = (int*)(dinv + N_NODES);   // [N]
    int*   cursor= deg + N_NODES;            // [N]
    float* psum  = (float*)(cursor + N_NODES);   // [64][256]
    int*   pmaxi = (int*)(psum + N_GRAPHS * F);  // [64][256]
    // ---- rest ----
    int*   row_ptr = pmaxi + N_GRAPHS * F;   // [N+1]
    int*   btot  = row_ptr + N_NODES + 1;    // [256]
    uint2v* erec = (uint2v*)(btot + 256);    // [E] 8B records (6.4 MB)

    // ---- degree + norm + CSR (+ W casts fused); ONE memset for all zeroed buffers ----
    hipMemsetAsync(deg, 0, (2 * N_NODES + 2 * N_GRAPHS * F) * sizeof(int), stream);
    prep_w_deg<<<512 + (N_EDGES + 255) / 256, 256, 0, stream>>>(
        W1, W2, w1hi, w1lo, w2hi, w2lo, dst, deg);
    scan_blocks<<<SCAN_NB, 256, 0, stream>>>(deg, row_ptr, btot, dinv);
    scan_totals<<<1, 256, 0, stream>>>(btot);
    add_offsets<<<SCAN_NB, 256, 0, stream>>>(row_ptr, btot);
    bucket_edges<<<(N_EDGES + 255) / 256, 256, 0, stream>>>(src, dst, dinv, row_ptr,
                                                            cursor, erec);

    int ggemm = (N_NODES + BM - 1) / BM;      // 782
    int ngb = N_NODES / 4;                    // 12500 blocks of 4 waves

    // ---- layer 1 ----
    gemm_mfma<<<ggemm, 256, 0, stream>>>(x, w1hi, w1lo, hbf, N_NODES);
    gather_bf16<<<ngb, 256, 0, stream>>>(row_ptr, erec, dinv, hbf, b1, h1bf);

    // ---- layer 2 ----
    gemm_mfma_bf16<<<ggemm, 256, 0, stream>>>(h1bf, w2hi, w2lo, hbf, N_NODES);
    gather_bf16<<<ngb, 256, 0, stream>>>(row_ptr, erec, dinv, hbf, b2, h2bf);

    // ---- pooling + classifier ----
    pool_partial<<<dim3(N_GRAPHS, POOL_CHUNKS), 64, 0, stream>>>(h2bf, batch, psum, pmaxi);
    final_gemm<<<N_GRAPHS, F_OUT, 0, stream>>>(psum, pmaxi, batch, Wfc, bfc, out);
}

// Round 13
// 412.810 us; speedup vs baseline: 1.1508x; 1.0227x over previous
//
#include <hip/hip_runtime.h>

#define N_NODES 50000
#define N_EDGES 800000
#define N_GRAPHS 64
#define F 256        // F_IN == F_HID
#define F_OUT 128
#define G_DIM 768    // 3*F
#define SCAN_NB ((N_NODES + 255) / 256)   // 196
#define POOL_CHUNKS 16

typedef unsigned short ushort_t;
typedef short short8 __attribute__((ext_vector_type(8)));
typedef unsigned short ushort8 __attribute__((ext_vector_type(8)));
typedef unsigned short ushort4v __attribute__((ext_vector_type(4)));
typedef float float4v __attribute__((ext_vector_type(4)));
typedef unsigned int uint2v __attribute__((ext_vector_type(2)));

// ---- bf16 helpers (RNE) ----
__device__ __forceinline__ unsigned short f2bf(float f) {
    unsigned int u = __float_as_uint(f);
    u += 0x7FFFu + ((u >> 16) & 1u);
    return (unsigned short)(u >> 16);
}
__device__ __forceinline__ float bf2f(unsigned short s) {
    return __uint_as_float(((unsigned int)s) << 16);
}

// ---- async global->LDS, 16B per lane; LDS dest = wave-uniform base + lane*16 ----
__device__ __forceinline__ void gld_lds16(const void* gsrc, void* ldst) {
    __builtin_amdgcn_global_load_lds(
        (const __attribute__((address_space(1))) unsigned int*)gsrc,
        (__attribute__((address_space(3))) unsigned int*)ldst, 16, 0, 0);
}

// ---------------- fused: W1/W2 transposed hi/lo cast (blocks 0..511) + degree count ----------------
__global__ void prep_w_deg(const float* __restrict__ W1, const float* __restrict__ W2,
                           short* __restrict__ hi1, short* __restrict__ lo1,
                           short* __restrict__ hi2, short* __restrict__ lo2,
                           const int* __restrict__ dst, int* __restrict__ deg) {
    int blk = blockIdx.x;
    if (blk < 512) {
        const float* W = (blk < 256) ? W1 : W2;
        short* hi = (blk < 256) ? hi1 : hi2;
        short* lo = (blk < 256) ? lo1 : lo2;
        int n = blk & 255;
        int k = threadIdx.x;
        float v = W[k * 256 + n];
        unsigned short h = f2bf(v);
        hi[n * 256 + k] = (short)h;
        lo[n * 256 + k] = (short)f2bf(v - bf2f(h));
    } else {
        int e = (blk - 512) * 256 + threadIdx.x;
        if (e < N_EDGES) atomicAdd(&deg[dst[e]], 1);
    }
}

// ---------------- scan blocks + fused dinv (btot holds RAW per-block sums) ----------------
__global__ void scan_blocks(const int* __restrict__ deg, int* __restrict__ row_ptr,
                            int* __restrict__ block_tot, float* __restrict__ dinv) {
    __shared__ int sd[256];
    int t = threadIdx.x;
    int idx = blockIdx.x * 256 + t;
    int v = (idx < N_NODES) ? deg[idx] : 0;
    if (idx < N_NODES) dinv[idx] = rsqrtf((float)(v + 1));   // +1 self-loop
    sd[t] = v;
    __syncthreads();
    for (int off = 1; off < 256; off <<= 1) {
        int a = (t >= off) ? sd[t - off] : 0;
        __syncthreads();
        sd[t] += a;
        __syncthreads();
    }
    if (idx < N_NODES) row_ptr[idx] = sd[t] - v;
    if (t == 255) block_tot[blockIdx.x] = sd[255];
}

// ---------------- add block offsets; each block reduces btot[0..blk) itself ----------------
__global__ void add_offsets(int* __restrict__ row_ptr, const int* __restrict__ block_tot) {
    __shared__ int sd[256];
    int t = threadIdx.x;
    int blk = blockIdx.x;
    sd[t] = (t < blk && t < SCAN_NB) ? block_tot[t] : 0;
    __syncthreads();
    for (int off = 128; off > 0; off >>= 1) {
        if (t < off) sd[t] += sd[t + off];
        __syncthreads();
    }
    int base = sd[0];
    int idx = blk * 256 + t;
    if (idx < N_NODES) row_ptr[idx] += base;
    if (idx == 0) row_ptr[N_NODES] = N_EDGES;
}

// ---------------- bucket edges into CSR order; combined 8B record ----------------
// erec[pos] = { float bits of norm (dinv[s]*dinv[d]), src index }
__global__ void bucket_edges(const int* __restrict__ src, const int* __restrict__ dst,
                             const float* __restrict__ dinv,
                             const int* __restrict__ row_ptr, int* __restrict__ cursor,
                             uint2v* __restrict__ erec) {
    int e = blockIdx.x * blockDim.x + threadIdx.x;
    if (e < N_EDGES) {
        int d = dst[e];
        int s = src[e];
        int pos = row_ptr[d] + atomicAdd(&cursor[d], 1);
        uint2v r;
        r.x = __float_as_uint(dinv[s] * dinv[d]);
        r.y = (unsigned)s;
        erec[pos] = r;
    }
}

// ---------------- GEMM1: split-bf16 MFMA, fp32 A, A-prefetch pipeline ----------------
// hbf[M,256] = bf16( A[M,256] @ W[256,256] ); A fp32 row-major, W transposed hi/lo bf16.
#define BM 64
#define BK 32
__global__ __launch_bounds__(256) void gemm_mfma(
        const float* __restrict__ A,
        const short* __restrict__ Bthi, const short* __restrict__ Btlo,
        ushort_t* __restrict__ hbf, int M) {
    __shared__ short sAh[BM * BK], sAl[BM * BK];       // 4KB + 4KB
    __shared__ short sBh[256 * BK], sBl[256 * BK];     // 16KB + 16KB
    int tid = threadIdx.x;
    int wave = tid >> 6, lane = tid & 63;
    int q = lane >> 4, t = lane & 15;
    int row0 = blockIdx.x * BM;
    int wc = wave * 64;            // wave's 64-col slice of N=256

    int lrow = lane >> 2;          // 0..15 (B staging)
    int lk = (lane & 3) * 8;       // k offset (shorts)
    int ar = tid >> 2;             // A staging: row 0..63
    int ak = (tid & 3) * 8;        // A staging: 8 floats at kt+ak

    int ga = row0 + ar; if (ga >= M) ga = M - 1;       // clamp; never stored
    const float* abase = &A[(size_t)ga * 256 + ak];
    // preload A(kt=0)
    float4 a0 = *(const float4*)(abase);
    float4 a1 = *(const float4*)(abase + 4);

    float4v acc[4][4] = {};
    for (int kt = 0; kt < 256; kt += BK) {
        // ---- B tile: async global->LDS ----
#pragma unroll
        for (int j = 0; j < 4; ++j) {
            int n = wave * 64 + j * 16 + lrow;
            size_t boff = (size_t)n * 256 + kt + lk;
            int ldso = wave * 2048 + j * 512 + lane * 8;
            gld_lds16(&Bthi[boff], &sBh[ldso]);
            gld_lds16(&Btlo[boff], &sBl[ldso]);
        }
        // ---- split current A regs once, write short8 hi/lo to LDS ----
        {
            short8 h, l;
            unsigned short hh;
            hh = f2bf(a0.x); h[0] = (short)hh; l[0] = (short)f2bf(a0.x - bf2f(hh));
            hh = f2bf(a0.y); h[1] = (short)hh; l[1] = (short)f2bf(a0.y - bf2f(hh));
            hh = f2bf(a0.z); h[2] = (short)hh; l[2] = (short)f2bf(a0.z - bf2f(hh));
            hh = f2bf(a0.w); h[3] = (short)hh; l[3] = (short)f2bf(a0.w - bf2f(hh));
            hh = f2bf(a1.x); h[4] = (short)hh; l[4] = (short)f2bf(a1.x - bf2f(hh));
            hh = f2bf(a1.y); h[5] = (short)hh; l[5] = (short)f2bf(a1.y - bf2f(hh));
            hh = f2bf(a1.z); h[6] = (short)hh; l[6] = (short)f2bf(a1.z - bf2f(hh));
            hh = f2bf(a1.w); h[7] = (short)hh; l[7] = (short)f2bf(a1.w - bf2f(hh));
            *(short8*)&sAh[ar * BK + ak] = h;
            *(short8*)&sAl[ar * BK + ak] = l;
        }
        // ---- prefetch next A tile into regs (stays in flight across barrier) ----
        float4 na0 = a0, na1 = a1;
        if (kt + BK < 256) {
            na0 = *(const float4*)(abase + kt + BK);
            na1 = *(const float4*)(abase + kt + BK + 4);
        }
        __syncthreads();
        short8 ah[4], al[4], bh[4], bl[4];
#pragma unroll
        for (int mi = 0; mi < 4; ++mi) {
            int r = mi * 16 + t;
            ah[mi] = *(const short8*)&sAh[r * BK + q * 8];
            al[mi] = *(const short8*)&sAl[r * BK + q * 8];
        }
#pragma unroll
        for (int ni = 0; ni < 4; ++ni) {
            int n = wc + ni * 16 + t;
            bh[ni] = *(const short8*)&sBh[n * BK + q * 8];
            bl[ni] = *(const short8*)&sBl[n * BK + q * 8];
        }
#pragma unroll
        for (int mi = 0; mi < 4; ++mi)
#pragma unroll
            for (int ni = 0; ni < 4; ++ni) {
                acc[mi][ni] = __builtin_amdgcn_mfma_f32_16x16x32_bf16(ah[mi], bh[ni], acc[mi][ni], 0, 0, 0);
                acc[mi][ni] = __builtin_amdgcn_mfma_f32_16x16x32_bf16(ah[mi], bl[ni], acc[mi][ni], 0, 0, 0);
                acc[mi][ni] = __builtin_amdgcn_mfma_f32_16x16x32_bf16(al[mi], bh[ni], acc[mi][ni], 0, 0, 0);
            }
        __syncthreads();
        a0 = na0; a1 = na1;
    }
#pragma unroll
    for (int mi = 0; mi < 4; ++mi) {
        int gr0 = row0 + mi * 16 + q * 4;
#pragma unroll
        for (int rr = 0; rr < 4; ++rr) {
            int gr = gr0 + rr;
            if (gr < M) {
#pragma unroll
                for (int ni = 0; ni < 4; ++ni)
                    hbf[(size_t)gr * 256 + wc + ni * 16 + t] = f2bf(acc[mi][ni][rr]);
            }
        }
    }
}

// ---------------- GEMM2: bf16 A (VGPR-mediated, prefetch pipeline), 2 MFMAs ----------------
__global__ __launch_bounds__(256) void gemm_mfma_bf16(
        const ushort_t* __restrict__ A,   // [M,256] bf16
        const short* __restrict__ Bthi, const short* __restrict__ Btlo,
        ushort_t* __restrict__ hbf, int M) {
    __shared__ short sA[BM * BK];                      // 4KB
    __shared__ short sBh[256 * BK], sBl[256 * BK];     // 16KB + 16KB
    int tid = threadIdx.x;
    int wave = tid >> 6, lane = tid & 63;
    int q = lane >> 4, t = lane & 15;
    int row0 = blockIdx.x * BM;
    int wc = wave * 64;

    int lrow = lane >> 2;          // 0..15 (B staging)
    int lk = (lane & 3) * 8;       // k offset (shorts)
    int ar = tid >> 2;             // A staging: row 0..63
    int ak = (tid & 3) * 8;        // 8 shorts at kt+ak

    int ga = row0 + ar; if (ga >= M) ga = M - 1;
    const ushort_t* abase = &A[(size_t)ga * 256 + ak];
    ushort8 a0 = *(const ushort8*)(abase);

    float4v acc[4][4] = {};
    for (int kt = 0; kt < 256; kt += BK) {
#pragma unroll
        for (int j = 0; j < 4; ++j) {
            int n = wave * 64 + j * 16 + lrow;
            size_t boff = (size_t)n * 256 + kt + lk;
            int ldso = wave * 2048 + j * 512 + lane * 8;
            gld_lds16(&Bthi[boff], &sBh[ldso]);
            gld_lds16(&Btlo[boff], &sBl[ldso]);
        }
        *(ushort8*)&sA[ar * BK + ak] = a0;
        ushort8 na = a0;
        if (kt + BK < 256) na = *(const ushort8*)(abase + kt + BK);
        __syncthreads();
        short8 ah[4], bh[4], bl[4];
#pragma unroll
        for (int mi = 0; mi < 4; ++mi) {
            int r = mi * 16 + t;
            ah[mi] = *(const short8*)&sA[r * BK + q * 8];
        }
#pragma unroll
        for (int ni = 0; ni < 4; ++ni) {
            int n = wc + ni * 16 + t;
            bh[ni] = *(const short8*)&sBh[n * BK + q * 8];
            bl[ni] = *(const short8*)&sBl[n * BK + q * 8];
        }
#pragma unroll
        for (int mi = 0; mi < 4; ++mi)
#pragma unroll
            for (int ni = 0; ni < 4; ++ni) {
                acc[mi][ni] = __builtin_amdgcn_mfma_f32_16x16x32_bf16(ah[mi], bh[ni], acc[mi][ni], 0, 0, 0);
                acc[mi][ni] = __builtin_amdgcn_mfma_f32_16x16x32_bf16(ah[mi], bl[ni], acc[mi][ni], 0, 0, 0);
            }
        __syncthreads();
        a0 = na;
    }
#pragma unroll
    for (int mi = 0; mi < 4; ++mi) {
        int gr0 = row0 + mi * 16 + q * 4;
#pragma unroll
        for (int rr = 0; rr < 4; ++rr) {
            int gr = gr0 + rr;
            if (gr < M) {
#pragma unroll
                for (int ni = 0; ni < 4; ++ni)
                    hbf[(size_t)gr * 256 + wc + ni * 16 + t] = f2bf(acc[mi][ni][rr]);
            }
        }
    }
}

// -------- CSR gather over bf16 h; 2 edges per wave-iteration; fused epilogue; bf16 out --------
__global__ __launch_bounds__(256) void gather_bf16(
        const int* __restrict__ row_ptr, const uint2v* __restrict__ erec,
        const float* __restrict__ dinv,
        const ushort_t* __restrict__ hbf, const float* __restrict__ b,
        ushort_t* __restrict__ outBf) {
    int wave = threadIdx.x >> 6;
    int node = blockIdx.x * 4 + wave;      // N_NODES % 4 == 0
    int lane = threadIdx.x & 63;
    int g = lane >> 5;                      // half-wave: which of the 2 edges
    int hl = lane & 31;                     // feats hl*8 .. hl*8+7
    int beg = row_ptr[node], end = row_ptr[node + 1];
    float dd = dinv[node];
    float acc[8] = {};
    for (int cbeg = beg; cbeg < end; cbeg += 64) {
        int n = end - cbeg; if (n > 64) n = 64;
        uint2v er = {0u, 0u};
        if (lane < n) er = __builtin_nontemporal_load(&erec[cbeg + lane]);
        int sv = (int)er.y;
        float wv = __uint_as_float(er.x);
        for (int k = 0; k < n; k += 2) {
            int idx = k + g;                // <= 63 always; w==0 if idx>=n
            int s = __shfl(sv, idx);
            float w = __shfl(wv, idx);
            ushort8 hv = *(const ushort8*)&hbf[(size_t)s * 256 + hl * 8];
#pragma unroll
            for (int j = 0; j < 8; ++j)
                acc[j] = fmaf(bf2f(hv[j]), w, acc[j]);
        }
    }
#pragma unroll
    for (int j = 0; j < 8; ++j) acc[j] += __shfl_xor(acc[j], 32);
    if (g == 0) {
        ushort8 sf = *(const ushort8*)&hbf[(size_t)node * 256 + hl * 8];
        float ws = dd * dd;
        ushort8 hb;
#pragma unroll
        for (int j = 0; j < 8; ++j) {
            float v = fmaxf(fmaf(bf2f(sf[j]), ws, acc[j]) + b[hl * 8 + j], 0.f);
            hb[j] = f2bf(v);
        }
        *(ushort8*)&outBf[(size_t)node * 256 + hl * 8] = hb;
    }
}

// ---------------- parallel triple pooling over bf16 h (1 wave/block) ----------------
__global__ __launch_bounds__(64) void pool_partial(
        const ushort_t* __restrict__ h, const int* __restrict__ batch,
        float* __restrict__ psum, int* __restrict__ pmaxi) {
    int g = blockIdx.x;
    int chunk = blockIdx.y;
    int lane = threadIdx.x;  // 64; lane covers feats lane*4..lane*4+3
    int lo = 0, hi = N_NODES;
    while (lo < hi) { int mid = (lo + hi) >> 1; if (batch[mid] < g) lo = mid + 1; else hi = mid; }
    int start = lo;
    lo = 0; hi = N_NODES;
    while (lo < hi) { int mid = (lo + hi) >> 1; if (batch[mid] < g + 1) lo = mid + 1; else hi = mid; }
    int end = lo;
    int len = end - start;
    if (len <= 0) return;
    int per = (len + POOL_CHUNKS - 1) / POOL_CHUNKS;
    int cs = start + chunk * per;
    int ce = cs + per; if (ce > end) ce = end;
    if (cs >= ce) return;
    float4 sum = make_float4(0.f, 0.f, 0.f, 0.f);
    float4 mx  = make_float4(0.f, 0.f, 0.f, 0.f);
    for (int n = cs; n < ce; ++n) {
        ushort4v u = *(const ushort4v*)&h[(size_t)n * 256 + lane * 4];
        float vx = bf2f(u.x), vy = bf2f(u.y), vz = bf2f(u.z), vw = bf2f(u.w);
        sum.x += vx; sum.y += vy; sum.z += vz; sum.w += vw;
        mx.x = fmaxf(mx.x, vx); mx.y = fmaxf(mx.y, vy);
        mx.z = fmaxf(mx.z, vz); mx.w = fmaxf(mx.w, vw);
    }
    float* ps = &psum[g * F + lane * 4];
    atomicAdd(&ps[0], sum.x); atomicAdd(&ps[1], sum.y);
    atomicAdd(&ps[2], sum.z); atomicAdd(&ps[3], sum.w);
    int* pm = &pmaxi[g * F + lane * 4];
    atomicMax(&pm[0], __float_as_int(mx.x)); atomicMax(&pm[1], __float_as_int(mx.y));
    atomicMax(&pm[2], __float_as_int(mx.z)); atomicMax(&pm[3], __float_as_int(mx.w));
}

// ---------------- final GEMM: out[64,128] = [mean|max|sum] @ Wfc + bfc ----------------
__global__ void final_gemm(const float* __restrict__ psum, const int* __restrict__ pmaxi,
                           const int* __restrict__ batch,
                           const float* __restrict__ Wfc, const float* __restrict__ bfc,
                           float* __restrict__ out) {
    int g = blockIdx.x;   // 64
    int o = threadIdx.x;  // 128
    __shared__ float row[G_DIM];
    __shared__ int s_cnt;
    if (threadIdx.x == 0) {
        int lo = 0, hi = N_NODES;
        while (lo < hi) { int mid = (lo + hi) >> 1; if (batch[mid] < g) lo = mid + 1; else hi = mid; }
        int start = lo;
        lo = 0; hi = N_NODES;
        while (lo < hi) { int mid = (lo + hi) >> 1; if (batch[mid] < g + 1) lo = mid + 1; else hi = mid; }
        s_cnt = lo - start;
    }
    __syncthreads();
    float inv = 1.0f / fmaxf((float)s_cnt, 1.0f);
    for (int i = threadIdx.x; i < F; i += 128) {
        float s = psum[g * F + i];
        row[i]       = s * inv;
        row[F + i]   = __int_as_float(pmaxi[g * F + i]);
        row[2*F + i] = s;
    }
    __syncthreads();
    float acc = bfc[o];
    for (int k = 0; k < G_DIM; ++k) acc += row[k] * Wfc[k * F_OUT + o];
    out[g * F_OUT + o] = acc;
}

extern "C" void kernel_launch(void* const* d_in, const int* in_sizes, int n_in,
                              void* d_out, int out_size, void* d_ws, size_t ws_size,
                              hipStream_t stream) {
    const float* x    = (const float*)d_in[0];
    const int*   ei   = (const int*)d_in[1];
    const int*   batch= (const int*)d_in[2];
    const float* W1   = (const float*)d_in[4];
    const float* b1   = (const float*)d_in[5];
    const float* W2   = (const float*)d_in[6];
    const float* b2   = (const float*)d_in[7];
    const float* Wfc  = (const float*)d_in[8];
    const float* bfc  = (const float*)d_in[9];
    float* out = (float*)d_out;

    const int* src = ei;
    const int* dst = ei + N_EDGES;

    const size_t NF = (size_t)N_NODES * F;   // 12.8M

    ushort_t* hbf  = (ushort_t*)d_ws;        // [N,256] bf16 gemm out (25.6 MB)
    ushort_t* h1bf = hbf + NF;               // [N,256] bf16 gather1 out; reused as h2bf
    ushort_t* h2bf = h1bf;                   //   (h1 consumed by gemm2 before gather2 writes)
    short* w1hi  = (short*)(h1bf + NF);      // 4x 64K shorts
    short* w1lo  = w1hi + 65536;
    short* w2hi  = w1lo + 65536;
    short* w2lo  = w2hi + 65536;
    float* dinv  = (float*)(w2lo + 65536);   // [N]
    // ---- contiguous zero-init region: deg, cursor, psum, pmaxi ----
    int*   deg   = (int*)(dinv + N_NODES);   // [N]
    int*   cursor= deg + N_NODES;            // [N]
    float* psum  = (float*)(cursor + N_NODES);   // [64][256]
    int*   pmaxi = (int*)(psum + N_GRAPHS * F);  // [64][256]
    // ---- rest ----
    int*   row_ptr = pmaxi + N_GRAPHS * F;   // [N+1]
    int*   btot  = row_ptr + N_NODES + 1;    // [256]
    uint2v* erec = (uint2v*)(btot + 256);    // [E] 8B records (6.4 MB)

    // ---- degree + norm + CSR (+ W casts fused); ONE memset for all zeroed buffers ----
    hipMemsetAsync(deg, 0, (2 * N_NODES + 2 * N_GRAPHS * F) * sizeof(int), stream);
    prep_w_deg<<<512 + (N_EDGES + 255) / 256, 256, 0, stream>>>(
        W1, W2, w1hi, w1lo, w2hi, w2lo, dst, deg);
    scan_blocks<<<SCAN_NB, 256, 0, stream>>>(deg, row_ptr, btot, dinv);
    add_offsets<<<SCAN_NB, 256, 0, stream>>>(row_ptr, btot);
    bucket_edges<<<(N_EDGES + 255) / 256, 256, 0, stream>>>(src, dst, dinv, row_ptr,
                                                            cursor, erec);

    int ggemm = (N_NODES + BM - 1) / BM;      // 782
    int ngb = N_NODES / 4;                    // 12500 blocks of 4 waves

    // ---- layer 1 ----
    gemm_mfma<<<ggemm, 256, 0, stream>>>(x, w1hi, w1lo, hbf, N_NODES);
    gather_bf16<<<ngb, 256, 0, stream>>>(row_ptr, erec, dinv, hbf, b1, h1bf);

    // ---- layer 2 ----
    gemm_mfma_bf16<<<ggemm, 256, 0, stream>>>(h1bf, w2hi, w2lo, hbf, N_NODES);
    gather_bf16<<<ngb, 256, 0, stream>>>(row_ptr, erec, dinv, hbf, b2, h2bf);

    // ---- pooling + classifier ----
    pool_partial<<<dim3(N_GRAPHS, POOL_CHUNKS), 64, 0, stream>>>(h2bf, batch, psum, pmaxi);
    final_gemm<<<N_GRAPHS, F_OUT, 0, stream>>>(psum, pmaxi, batch, Wfc, bfc, out);
}

// Round 14
// 404.284 us; speedup vs baseline: 1.1751x; 1.0211x over previous
//
#include <hip/hip_runtime.h>

#define N_NODES 50000
#define N_EDGES 800000
#define N_GRAPHS 64
#define F 256        // F_IN == F_HID
#define F_OUT 128
#define G_DIM 768    // 3*F
#define SCAN_NB ((N_NODES + 255) / 256)   // 196
#define POOL_CHUNKS 32

typedef unsigned short ushort_t;
typedef short short8 __attribute__((ext_vector_type(8)));
typedef unsigned short ushort8 __attribute__((ext_vector_type(8)));
typedef unsigned short ushort4v __attribute__((ext_vector_type(4)));
typedef float float4v __attribute__((ext_vector_type(4)));

// ---- bf16 helpers (RNE) ----
__device__ __forceinline__ unsigned short f2bf(float f) {
    unsigned int u = __float_as_uint(f);
    u += 0x7FFFu + ((u >> 16) & 1u);
    return (unsigned short)(u >> 16);
}
__device__ __forceinline__ float bf2f(unsigned short s) {
    return __uint_as_float(((unsigned int)s) << 16);
}

// ---- async global->LDS, 16B per lane; LDS dest = wave-uniform base + lane*16 ----
__device__ __forceinline__ void gld_lds16(const void* gsrc, void* ldst) {
    __builtin_amdgcn_global_load_lds(
        (const __attribute__((address_space(1))) unsigned int*)gsrc,
        (__attribute__((address_space(3))) unsigned int*)ldst, 16, 0, 0);
}

// ---------------- fused: W1/W2 transposed hi/lo cast (blocks 0..511) + degree count ----------------
__global__ void prep_w_deg(const float* __restrict__ W1, const float* __restrict__ W2,
                           short* __restrict__ hi1, short* __restrict__ lo1,
                           short* __restrict__ hi2, short* __restrict__ lo2,
                           const int* __restrict__ dst, int* __restrict__ deg) {
    int blk = blockIdx.x;
    if (blk < 512) {
        const float* W = (blk < 256) ? W1 : W2;
        short* hi = (blk < 256) ? hi1 : hi2;
        short* lo = (blk < 256) ? lo1 : lo2;
        int n = blk & 255;
        int k = threadIdx.x;
        float v = W[k * 256 + n];
        unsigned short h = f2bf(v);
        hi[n * 256 + k] = (short)h;
        lo[n * 256 + k] = (short)f2bf(v - bf2f(h));
    } else {
        int e = (blk - 512) * 256 + threadIdx.x;
        if (e < N_EDGES) atomicAdd(&deg[dst[e]], 1);
    }
}

// ---------------- scan blocks + fused dinv (btot holds RAW per-block sums) ----------------
__global__ void scan_blocks(const int* __restrict__ deg, int* __restrict__ row_ptr,
                            int* __restrict__ block_tot, float* __restrict__ dinv) {
    __shared__ int sd[256];
    int t = threadIdx.x;
    int idx = blockIdx.x * 256 + t;
    int v = (idx < N_NODES) ? deg[idx] : 0;
    if (idx < N_NODES) dinv[idx] = rsqrtf((float)(v + 1));   // +1 self-loop
    sd[t] = v;
    __syncthreads();
    for (int off = 1; off < 256; off <<= 1) {
        int a = (t >= off) ? sd[t - off] : 0;
        __syncthreads();
        sd[t] += a;
        __syncthreads();
    }
    if (idx < N_NODES) row_ptr[idx] = sd[t] - v;
    if (t == 255) block_tot[blockIdx.x] = sd[255];
}

// ---------------- add block offsets; each block reduces btot[0..blk) itself ----------------
__global__ void add_offsets(int* __restrict__ row_ptr, const int* __restrict__ block_tot) {
    __shared__ int sd[256];
    int t = threadIdx.x;
    int blk = blockIdx.x;
    sd[t] = (t < blk && t < SCAN_NB) ? block_tot[t] : 0;
    __syncthreads();
    for (int off = 128; off > 0; off >>= 1) {
        if (t < off) sd[t] += sd[t + off];
        __syncthreads();
    }
    int base = sd[0];
    int idx = blk * 256 + t;
    if (idx < N_NODES) row_ptr[idx] += base;
    if (idx == 0) row_ptr[N_NODES] = N_EDGES;
}

// ---------------- bucket edges into CSR order; packed 4B record ----------------
// erec[pos] = src (low 16) | bf16(norm) (high 16)
__global__ void bucket_edges(const int* __restrict__ src, const int* __restrict__ dst,
                             const float* __restrict__ dinv,
                             const int* __restrict__ row_ptr, int* __restrict__ cursor,
                             unsigned int* __restrict__ erec) {
    int e = blockIdx.x * blockDim.x + threadIdx.x;
    if (e < N_EDGES) {
        int d = dst[e];
        int s = src[e];
        int pos = row_ptr[d] + atomicAdd(&cursor[d], 1);
        unsigned int w = (unsigned int)f2bf(dinv[s] * dinv[d]);
        erec[pos] = (unsigned int)s | (w << 16);
    }
}

// ---------------- GEMM1: split-bf16 MFMA, fp32 A, A-prefetch pipeline ----------------
// hbf[M,256] = bf16( A[M,256] @ W[256,256] ); A fp32 row-major, W transposed hi/lo bf16.
#define BM 64
#define BK 32
__global__ __launch_bounds__(256) void gemm_mfma(
        const float* __restrict__ A,
        const short* __restrict__ Bthi, const short* __restrict__ Btlo,
        ushort_t* __restrict__ hbf, int M) {
    __shared__ short sAh[BM * BK], sAl[BM * BK];       // 4KB + 4KB
    __shared__ short sBh[256 * BK], sBl[256 * BK];     // 16KB + 16KB
    int tid = threadIdx.x;
    int wave = tid >> 6, lane = tid & 63;
    int q = lane >> 4, t = lane & 15;
    int row0 = blockIdx.x * BM;
    int wc = wave * 64;            // wave's 64-col slice of N=256

    int lrow = lane >> 2;          // 0..15 (B staging)
    int lk = (lane & 3) * 8;       // k offset (shorts)
    int ar = tid >> 2;             // A staging: row 0..63
    int ak = (tid & 3) * 8;        // A staging: 8 floats at kt+ak

    int ga = row0 + ar; if (ga >= M) ga = M - 1;       // clamp; never stored
    const float* abase = &A[(size_t)ga * 256 + ak];
    float4 a0 = *(const float4*)(abase);
    float4 a1 = *(const float4*)(abase + 4);

    float4v acc[4][4] = {};
    for (int kt = 0; kt < 256; kt += BK) {
#pragma unroll
        for (int j = 0; j < 4; ++j) {
            int n = wave * 64 + j * 16 + lrow;
            size_t boff = (size_t)n * 256 + kt + lk;
            int ldso = wave * 2048 + j * 512 + lane * 8;
            gld_lds16(&Bthi[boff], &sBh[ldso]);
            gld_lds16(&Btlo[boff], &sBl[ldso]);
        }
        {
            short8 h, l;
            unsigned short hh;
            hh = f2bf(a0.x); h[0] = (short)hh; l[0] = (short)f2bf(a0.x - bf2f(hh));
            hh = f2bf(a0.y); h[1] = (short)hh; l[1] = (short)f2bf(a0.y - bf2f(hh));
            hh = f2bf(a0.z); h[2] = (short)hh; l[2] = (short)f2bf(a0.z - bf2f(hh));
            hh = f2bf(a0.w); h[3] = (short)hh; l[3] = (short)f2bf(a0.w - bf2f(hh));
            hh = f2bf(a1.x); h[4] = (short)hh; l[4] = (short)f2bf(a1.x - bf2f(hh));
            hh = f2bf(a1.y); h[5] = (short)hh; l[5] = (short)f2bf(a1.y - bf2f(hh));
            hh = f2bf(a1.z); h[6] = (short)hh; l[6] = (short)f2bf(a1.z - bf2f(hh));
            hh = f2bf(a1.w); h[7] = (short)hh; l[7] = (short)f2bf(a1.w - bf2f(hh));
            *(short8*)&sAh[ar * BK + ak] = h;
            *(short8*)&sAl[ar * BK + ak] = l;
        }
        float4 na0 = a0, na1 = a1;
        if (kt + BK < 256) {
            na0 = *(const float4*)(abase + kt + BK);
            na1 = *(const float4*)(abase + kt + BK + 4);
        }
        __syncthreads();
        short8 ah[4], al[4], bh[4], bl[4];
#pragma unroll
        for (int mi = 0; mi < 4; ++mi) {
            int r = mi * 16 + t;
            ah[mi] = *(const short8*)&sAh[r * BK + q * 8];
            al[mi] = *(const short8*)&sAl[r * BK + q * 8];
        }
#pragma unroll
        for (int ni = 0; ni < 4; ++ni) {
            int n = wc + ni * 16 + t;
            bh[ni] = *(const short8*)&sBh[n * BK + q * 8];
            bl[ni] = *(const short8*)&sBl[n * BK + q * 8];
        }
#pragma unroll
        for (int mi = 0; mi < 4; ++mi)
#pragma unroll
            for (int ni = 0; ni < 4; ++ni) {
                acc[mi][ni] = __builtin_amdgcn_mfma_f32_16x16x32_bf16(ah[mi], bh[ni], acc[mi][ni], 0, 0, 0);
                acc[mi][ni] = __builtin_amdgcn_mfma_f32_16x16x32_bf16(ah[mi], bl[ni], acc[mi][ni], 0, 0, 0);
                acc[mi][ni] = __builtin_amdgcn_mfma_f32_16x16x32_bf16(al[mi], bh[ni], acc[mi][ni], 0, 0, 0);
            }
        __syncthreads();
        a0 = na0; a1 = na1;
    }
#pragma unroll
    for (int mi = 0; mi < 4; ++mi) {
        int gr0 = row0 + mi * 16 + q * 4;
#pragma unroll
        for (int rr = 0; rr < 4; ++rr) {
            int gr = gr0 + rr;
            if (gr < M) {
#pragma unroll
                for (int ni = 0; ni < 4; ++ni)
                    hbf[(size_t)gr * 256 + wc + ni * 16 + t] = f2bf(acc[mi][ni][rr]);
            }
        }
    }
}

// ---------------- GEMM2: bf16 A fully preloaded to regs; 2 MFMAs ----------------
__global__ __launch_bounds__(256) void gemm_mfma_bf16(
        const ushort_t* __restrict__ A,   // [M,256] bf16
        const short* __restrict__ Bthi, const short* __restrict__ Btlo,
        ushort_t* __restrict__ hbf, int M) {
    __shared__ short sA[BM * BK];                      // 4KB
    __shared__ short sBh[256 * BK], sBl[256 * BK];     // 16KB + 16KB
    int tid = threadIdx.x;
    int wave = tid >> 6, lane = tid & 63;
    int q = lane >> 4, t = lane & 15;
    int row0 = blockIdx.x * BM;
    int wc = wave * 64;

    int lrow = lane >> 2;          // 0..15 (B staging)
    int lk = (lane & 3) * 8;       // k offset (shorts)
    int ar = tid >> 2;             // A staging: row 0..63
    int ak = (tid & 3) * 8;        // 8 shorts at kt+ak

    int ga = row0 + ar; if (ga >= M) ga = M - 1;
    const ushort_t* abase = &A[(size_t)ga * 256 + ak];
    // preload ALL of this thread's A (8 x 16B = 1 HBM round-trip, issued together)
    ushort8 areg[8];
#pragma unroll
    for (int i = 0; i < 8; ++i) areg[i] = *(const ushort8*)(abase + i * BK);

    float4v acc[4][4] = {};
#pragma unroll
    for (int ki = 0; ki < 8; ++ki) {
        int kt = ki * BK;
#pragma unroll
        for (int j = 0; j < 4; ++j) {
            int n = wave * 64 + j * 16 + lrow;
            size_t boff = (size_t)n * 256 + kt + lk;
            int ldso = wave * 2048 + j * 512 + lane * 8;
            gld_lds16(&Bthi[boff], &sBh[ldso]);
            gld_lds16(&Btlo[boff], &sBl[ldso]);
        }
        *(ushort8*)&sA[ar * BK + ak] = areg[ki];
        __syncthreads();
        short8 ah[4], bh[4], bl[4];
#pragma unroll
        for (int mi = 0; mi < 4; ++mi) {
            int r = mi * 16 + t;
            ah[mi] = *(const short8*)&sA[r * BK + q * 8];
        }
#pragma unroll
        for (int ni = 0; ni < 4; ++ni) {
            int n = wc + ni * 16 + t;
            bh[ni] = *(const short8*)&sBh[n * BK + q * 8];
            bl[ni] = *(const short8*)&sBl[n * BK + q * 8];
        }
#pragma unroll
        for (int mi = 0; mi < 4; ++mi)
#pragma unroll
            for (int ni = 0; ni < 4; ++ni) {
                acc[mi][ni] = __builtin_amdgcn_mfma_f32_16x16x32_bf16(ah[mi], bh[ni], acc[mi][ni], 0, 0, 0);
                acc[mi][ni] = __builtin_amdgcn_mfma_f32_16x16x32_bf16(ah[mi], bl[ni], acc[mi][ni], 0, 0, 0);
            }
        __syncthreads();
    }
#pragma unroll
    for (int mi = 0; mi < 4; ++mi) {
        int gr0 = row0 + mi * 16 + q * 4;
#pragma unroll
        for (int rr = 0; rr < 4; ++rr) {
            int gr = gr0 + rr;
            if (gr < M) {
#pragma unroll
                for (int ni = 0; ni < 4; ++ni)
                    hbf[(size_t)gr * 256 + wc + ni * 16 + t] = f2bf(acc[mi][ni][rr]);
            }
        }
    }
}

// -------- CSR gather over bf16 h; packed 4B edge records; fused epilogue; bf16 out --------
__global__ __launch_bounds__(256) void gather_bf16(
        const int* __restrict__ row_ptr, const unsigned int* __restrict__ erec,
        const float* __restrict__ dinv,
        const ushort_t* __restrict__ hbf, const float* __restrict__ b,
        ushort_t* __restrict__ outBf) {
    int wave = threadIdx.x >> 6;
    int node = blockIdx.x * 4 + wave;      // N_NODES % 4 == 0
    int lane = threadIdx.x & 63;
    int g = lane >> 5;                      // half-wave: which of the 2 edges
    int hl = lane & 31;                     // feats hl*8 .. hl*8+7
    int beg = row_ptr[node], end = row_ptr[node + 1];
    float dd = dinv[node];
    float acc[8] = {};
    for (int cbeg = beg; cbeg < end; cbeg += 64) {
        int n = end - cbeg; if (n > 64) n = 64;
        unsigned int ev = 0u;
        if (lane < n) ev = __builtin_nontemporal_load(&erec[cbeg + lane]);
        for (int k = 0; k < n; k += 2) {
            unsigned int er = (unsigned int)__shfl((int)ev, k + g);  // w==0 if slot empty
            int s = (int)(er & 0xFFFFu);
            float w = bf2f((unsigned short)(er >> 16));
            ushort8 hv = *(const ushort8*)&hbf[(size_t)s * 256 + hl * 8];
#pragma unroll
            for (int j = 0; j < 8; ++j)
                acc[j] = fmaf(bf2f(hv[j]), w, acc[j]);
        }
    }
#pragma unroll
    for (int j = 0; j < 8; ++j) acc[j] += __shfl_xor(acc[j], 32);
    if (g == 0) {
        ushort8 sf = *(const ushort8*)&hbf[(size_t)node * 256 + hl * 8];
        float ws = dd * dd;
        ushort8 hb;
#pragma unroll
        for (int j = 0; j < 8; ++j) {
            float v = fmaxf(fmaf(bf2f(sf[j]), ws, acc[j]) + b[hl * 8 + j], 0.f);
            hb[j] = f2bf(v);
        }
        *(ushort8*)&outBf[(size_t)node * 256 + hl * 8] = hb;
    }
}

// ---------------- parallel triple pooling over bf16 h (1 wave/block) ----------------
__global__ __launch_bounds__(64) void pool_partial(
        const ushort_t* __restrict__ h, const int* __restrict__ batch,
        float* __restrict__ psum, int* __restrict__ pmaxi) {
    int g = blockIdx.x;
    int chunk = blockIdx.y;
    int lane = threadIdx.x;  // 64; lane covers feats lane*4..lane*4+3
    int lo = 0, hi = N_NODES;
    while (lo < hi) { int mid = (lo + hi) >> 1; if (batch[mid] < g) lo = mid + 1; else hi = mid; }
    int start = lo;
    lo = 0; hi = N_NODES;
    while (lo < hi) { int mid = (lo + hi) >> 1; if (batch[mid] < g + 1) lo = mid + 1; else hi = mid; }
    int end = lo;
    int len = end - start;
    if (len <= 0) return;
    int per = (len + POOL_CHUNKS - 1) / POOL_CHUNKS;
    int cs = start + chunk * per;
    int ce = cs + per; if (ce > end) ce = end;
    if (cs >= ce) return;
    float4 sum = make_float4(0.f, 0.f, 0.f, 0.f);
    float4 mx  = make_float4(0.f, 0.f, 0.f, 0.f);
    for (int n = cs; n < ce; ++n) {
        ushort4v u = *(const ushort4v*)&h[(size_t)n * 256 + lane * 4];
        float vx = bf2f(u.x), vy = bf2f(u.y), vz = bf2f(u.z), vw = bf2f(u.w);
        sum.x += vx; sum.y += vy; sum.z += vz; sum.w += vw;
        mx.x = fmaxf(mx.x, vx); mx.y = fmaxf(mx.y, vy);
        mx.z = fmaxf(mx.z, vz); mx.w = fmaxf(mx.w, vw);
    }
    float* ps = &psum[g * F + lane * 4];
    atomicAdd(&ps[0], sum.x); atomicAdd(&ps[1], sum.y);
    atomicAdd(&ps[2], sum.z); atomicAdd(&ps[3], sum.w);
    int* pm = &pmaxi[g * F + lane * 4];
    atomicMax(&pm[0], __float_as_int(mx.x)); atomicMax(&pm[1], __float_as_int(mx.y));
    atomicMax(&pm[2], __float_as_int(mx.z)); atomicMax(&pm[3], __float_as_int(mx.w));
}

// ---------------- final GEMM: out[64,128] = [mean|max|sum] @ Wfc + bfc ----------------
__global__ void final_gemm(const float* __restrict__ psum, const int* __restrict__ pmaxi,
                           const int* __restrict__ batch,
                           const float* __restrict__ Wfc, const float* __restrict__ bfc,
                           float* __restrict__ out) {
    int g = blockIdx.x;   // 64
    int o = threadIdx.x;  // 128
    __shared__ float row[G_DIM];
    __shared__ int s_cnt;
    if (threadIdx.x == 0) {
        int lo = 0, hi = N_NODES;
        while (lo < hi) { int mid = (lo + hi) >> 1; if (batch[mid] < g) lo = mid + 1; else hi = mid; }
        int start = lo;
        lo = 0; hi = N_NODES;
        while (lo < hi) { int mid = (lo + hi) >> 1; if (batch[mid] < g + 1) lo = mid + 1; else hi = mid; }
        s_cnt = lo - start;
    }
    __syncthreads();
    float inv = 1.0f / fmaxf((float)s_cnt, 1.0f);
    for (int i = threadIdx.x; i < F; i += 128) {
        float s = psum[g * F + i];
        row[i]       = s * inv;
        row[F + i]   = __int_as_float(pmaxi[g * F + i]);
        row[2*F + i] = s;
    }
    __syncthreads();
    float acc = bfc[o];
    for (int k = 0; k < G_DIM; ++k) acc += row[k] * Wfc[k * F_OUT + o];
    out[g * F_OUT + o] = acc;
}

extern "C" void kernel_launch(void* const* d_in, const int* in_sizes, int n_in,
                              void* d_out, int out_size, void* d_ws, size_t ws_size,
                              hipStream_t stream) {
    const float* x    = (const float*)d_in[0];
    const int*   ei   = (const int*)d_in[1];
    const int*   batch= (const int*)d_in[2];
    const float* W1   = (const float*)d_in[4];
    const float* b1   = (const float*)d_in[5];
    const float* W2   = (const float*)d_in[6];
    const float* b2   = (const float*)d_in[7];
    const float* Wfc  = (const float*)d_in[8];
    const float* bfc  = (const float*)d_in[9];
    float* out = (float*)d_out;

    const int* src = ei;
    const int* dst = ei + N_EDGES;

    const size_t NF = (size_t)N_NODES * F;   // 12.8M

    ushort_t* hbf  = (ushort_t*)d_ws;        // [N,256] bf16 gemm out (25.6 MB)
    ushort_t* h1bf = hbf + NF;               // [N,256] bf16 gather1 out; reused as h2bf
    ushort_t* h2bf = h1bf;                   //   (h1 consumed by gemm2 before gather2 writes)
    short* w1hi  = (short*)(h1bf + NF);      // 4x 64K shorts
    short* w1lo  = w1hi + 65536;
    short* w2hi  = w1lo + 65536;
    short* w2lo  = w2hi + 65536;
    float* dinv  = (float*)(w2lo + 65536);   // [N]
    // ---- contiguous zero-init region: deg, cursor, psum, pmaxi ----
    int*   deg   = (int*)(dinv + N_NODES);   // [N]
    int*   cursor= deg + N_NODES;            // [N]
    float* psum  = (float*)(cursor + N_NODES);   // [64][256]
    int*   pmaxi = (int*)(psum + N_GRAPHS * F);  // [64][256]
    // ---- rest ----
    int*   row_ptr = pmaxi + N_GRAPHS * F;   // [N+1]
    int*   btot  = row_ptr + N_NODES + 1;    // [256]
    unsigned int* erec = (unsigned int*)(btot + 256);   // [E] 4B records (3.2 MB)

    // ---- degree + norm + CSR (+ W casts fused); ONE memset for all zeroed buffers ----
    hipMemsetAsync(deg, 0, (2 * N_NODES + 2 * N_GRAPHS * F) * sizeof(int), stream);
    prep_w_deg<<<512 + (N_EDGES + 255) / 256, 256, 0, stream>>>(
        W1, W2, w1hi, w1lo, w2hi, w2lo, dst, deg);
    scan_blocks<<<SCAN_NB, 256, 0, stream>>>(deg, row_ptr, btot, dinv);
    add_offsets<<<SCAN_NB, 256, 0, stream>>>(row_ptr, btot);
    bucket_edges<<<(N_EDGES + 255) / 256, 256, 0, stream>>>(src, dst, dinv, row_ptr,
                                                            cursor, erec);

    int ggemm = (N_NODES + BM - 1) / BM;      // 782
    int ngb = N_NODES / 4;                    // 12500 blocks of 4 waves

    // ---- layer 1 ----
    gemm_mfma<<<ggemm, 256, 0, stream>>>(x, w1hi, w1lo, hbf, N_NODES);
    gather_bf16<<<ngb, 256, 0, stream>>>(row_ptr, erec, dinv, hbf, b1, h1bf);

    // ---- layer 2 ----
    gemm_mfma_bf16<<<ggemm, 256, 0, stream>>>(h1bf, w2hi, w2lo, hbf, N_NODES);
    gather_bf16<<<ngb, 256, 0, stream>>>(row_ptr, erec, dinv, hbf, b2, h2bf);

    // ---- pooling + classifier ----
    pool_partial<<<dim3(N_GRAPHS, POOL_CHUNKS), 64, 0, stream>>>(h2bf, batch, psum, pmaxi);
    final_gemm<<<N_GRAPHS, F_OUT, 0, stream>>>(psum, pmaxi, batch, Wfc, bfc, out);
}